// Round 2
// baseline (3359.044 us; speedup 1.0000x reference)
//
#include <hip/hip_runtime.h>
#include <hip/hip_bf16.h>
#include <hip/hip_cooperative_groups.h>
#include <stdint.h>

namespace cg = cooperative_groups;

#define B_ 256
#define S_ 64
#define D_ 256
#define H_ 1024
#define O_ 512
#define G_ 3072          // 3*H
#define BH_ (B_ * H_)    // 262144

typedef unsigned short u16;
typedef __attribute__((ext_vector_type(8))) short bf16x8;
typedef __attribute__((ext_vector_type(4))) float f32x4;

#define MFMA16(a, b, c) __builtin_amdgcn_mfma_f32_16x16x32_bf16((a), (b), (c), 0, 0, 0)

__device__ __forceinline__ u16 f2b(float f) {
    union { float f; uint32_t u; } v; v.f = f;
    uint32_t u = v.u;
    uint32_t r = (u + 0x7fffu + ((u >> 16) & 1u)) >> 16;   // RNE
    return (u16)r;
}

__device__ __forceinline__ void gl_lds16(const u16* g, u16* l) {
    __builtin_amdgcn_global_load_lds(
        (const __attribute__((address_space(1))) unsigned int*)g,
        (__attribute__((address_space(3))) unsigned int*)l, 16, 0, 0);
}

// ---------------- prep kernels ----------------

__global__ void k_conv(const float* __restrict__ s, u16* __restrict__ d, int n4) {
    int i = blockIdx.x * blockDim.x + threadIdx.x;
    int st = gridDim.x * blockDim.x;
    for (; i < n4; i += st) {
        float4 v = ((const float4*)s)[i];
        ushort4 o;
        o.x = f2b(v.x); o.y = f2b(v.y); o.z = f2b(v.z); o.w = f2b(v.w);
        ((ushort4*)d)[i] = o;
    }
}

// lin_w [S][H][O] f32 -> [S][O][H] bf16
__global__ __launch_bounds__(256) void k_twl(const float* __restrict__ w, u16* __restrict__ o) {
    __shared__ float tile[32][33];
    int bid = blockIdx.x;
    int t = bid >> 9;            // 512 tiles / t  (32 j-tiles x 16 o-tiles)
    int rem = bid & 511;
    int j0 = (rem >> 4) << 5;
    int o0 = (rem & 15) << 5;
    int tx = threadIdx.x & 31, ty = threadIdx.x >> 5;
    const float* base = w + (size_t)t * (H_ * O_);
#pragma unroll
    for (int i = 0; i < 4; ++i) {
        int r = ty + (i << 3);
        tile[r][tx] = base[(size_t)(j0 + r) * O_ + o0 + tx];
    }
    __syncthreads();
    u16* ob = o + (size_t)t * (O_ * H_);
#pragma unroll
    for (int i = 0; i < 4; ++i) {
        int r = ty + (i << 3);
        ob[(size_t)(o0 + r) * H_ + j0 + tx] = f2b(tile[tx][r]);
    }
}

// ---------------- persistent cooperative GRU ----------------

struct GruArgs {
    const u16* Xb;
    const u16 *Wi0, *Wh0, *Wi1, *Wh1, *Wi2, *Wh2;
    const float *bi0, *bh0, *bi1, *bh1, *bi2, *bh2;
    u16 *h0b, *h1b, *h2a;        // bf16 state (h2a: 65 slots, slot t+1 = time t)
    float *h0f, *h1f, *h2f;      // fp32 state (double-buffered)
};

__global__ __launch_bounds__(512, 2) void k_gru(GruArgs p) {
    // XCD-affinity mapping: wg%8 -> XCD.  Per XCD: 3 cells x 2 j-tiles x 4 b-tiles.
    int w = blockIdx.x;
    int xcd = w & 7;
    int q = w >> 3;              // 0..23
    int cell = q >> 3;           // 0..2
    int r = q & 7;
    int j0 = ((xcd << 1) + (r >> 2)) << 6;   // 16 j-tiles of 64
    int b0 = (r & 3) << 6;                   // 4 b-tiles of 64

    const u16 *Wi, *Wh;
    const float *bi, *bh;
    int K0;
    if (cell == 0)      { Wi = p.Wi0; Wh = p.Wh0; bi = p.bi0; bh = p.bh0; K0 = D_; }
    else if (cell == 1) { Wi = p.Wi1; Wh = p.Wh1; bi = p.bi1; bh = p.bh1; K0 = H_; }
    else                { Wi = p.Wi2; Wh = p.Wh2; bi = p.bi2; bh = p.bh2; K0 = H_; }
    const int nX = K0 >> 6;
    const int nSup = nX + (H_ >> 6);

    __shared__ u16 lds[2][4][64 * 64];   // [dbuf][A,Wr,Wz,Wn][64 rows x 64 k] = 64 KiB

    int tid = threadIdx.x;
    int srow = tid >> 3;                           // staging row 0..63
    int soff = ((tid & 7) ^ (srow & 7)) << 3;      // swizzled 16B chunk (elems)

    int wid = tid >> 6, lane = tid & 63;
    int g = wid >> 2;                              // K-half group (0/1)
    int quad = wid & 3;
    int wr = (quad >> 1) << 5, wc = (quad & 1) << 5;
    int fr = lane & 15, kc = lane >> 4;

    int aoff[2], boff[2];
#pragma unroll
    for (int m = 0; m < 2; ++m) {
        int row = wr + 16 * m + fr;
        aoff[m] = row * 64 + ((((g << 2) + kc) ^ (row & 7)) << 3);
    }
#pragma unroll
    for (int n = 0; n < 2; ++n) {
        int col = wc + 16 * n + fr;
        boff[n] = col * 64 + ((((g << 2) + kc) ^ (col & 7)) << 3);
    }

    cg::grid_group grid = cg::this_grid();

    for (int k = 0; k < S_ + 2; ++k) {
        int t = k - cell;
        if (t >= 0 && t < S_) {
            const u16* Ax; int ldax;
            const u16* Ah;
            const float* Hpf;
            u16* hob; float* hof;
            if (cell == 0) {
                Ax = p.Xb + (size_t)b0 * (S_ * D_) + t * D_; ldax = S_ * D_;
                Ah  = p.h0b + ((t + 1) & 1) * BH_ + (size_t)b0 * H_;
                Hpf = p.h0f + ((t + 1) & 1) * BH_;
                hob = p.h0b + (t & 1) * BH_;
                hof = p.h0f + (t & 1) * BH_;
            } else if (cell == 1) {
                Ax = p.h0b + (t & 1) * BH_ + (size_t)b0 * H_; ldax = H_;
                Ah  = p.h1b + ((t + 1) & 1) * BH_ + (size_t)b0 * H_;
                Hpf = p.h1f + ((t + 1) & 1) * BH_;
                hob = p.h1b + (t & 1) * BH_;
                hof = p.h1f + (t & 1) * BH_;
            } else {
                Ax = p.h1b + (t & 1) * BH_ + (size_t)b0 * H_; ldax = H_;
                Ah  = p.h2a + (size_t)t * BH_ + (size_t)b0 * H_;
                Hpf = p.h2f + ((t + 1) & 1) * BH_;
                hob = p.h2a + (size_t)(t + 1) * BH_;
                hof = p.h2f + (t & 1) * BH_;
            }

            auto stage = [&](int s, int nb) {
                const u16 *arow, *wrow; size_t gs;
                if (s < nX) {
                    int kk = s << 6;
                    arow = Ax + (size_t)srow * ldax + kk + soff;
                    wrow = Wi + (size_t)(j0 + srow) * K0 + kk + soff;
                    gs = (size_t)H_ * K0;
                } else {
                    int kk = (s - nX) << 6;
                    arow = Ah + (size_t)srow * H_ + kk + soff;
                    wrow = Wh + (size_t)(j0 + srow) * H_ + kk + soff;
                    gs = (size_t)H_ * H_;
                }
                gl_lds16(arow,          &lds[nb][0][tid << 3]);
                gl_lds16(wrow,          &lds[nb][1][tid << 3]);
                gl_lds16(wrow + gs,     &lds[nb][2][tid << 3]);
                gl_lds16(wrow + 2 * gs, &lds[nb][3][tid << 3]);
            };

            f32x4 accR[2][2] = {}, accZ[2][2] = {}, accI[2][2] = {}, accN[2][2] = {};

            stage(0, 0);
            __syncthreads();

            for (int s = 0; s < nSup; ++s) {
                int cur = s & 1;
                if (s + 1 < nSup) stage(s + 1, cur ^ 1);

                bf16x8 a0 = *(const bf16x8*)&lds[cur][0][aoff[0]];
                bf16x8 a1 = *(const bf16x8*)&lds[cur][0][aoff[1]];
                bf16x8 r0 = *(const bf16x8*)&lds[cur][1][boff[0]];
                bf16x8 r1 = *(const bf16x8*)&lds[cur][1][boff[1]];
                bf16x8 z0 = *(const bf16x8*)&lds[cur][2][boff[0]];
                bf16x8 z1 = *(const bf16x8*)&lds[cur][2][boff[1]];
                bf16x8 q0 = *(const bf16x8*)&lds[cur][3][boff[0]];
                bf16x8 q1 = *(const bf16x8*)&lds[cur][3][boff[1]];

                accR[0][0] = MFMA16(a0, r0, accR[0][0]);
                accR[0][1] = MFMA16(a0, r1, accR[0][1]);
                accR[1][0] = MFMA16(a1, r0, accR[1][0]);
                accR[1][1] = MFMA16(a1, r1, accR[1][1]);
                accZ[0][0] = MFMA16(a0, z0, accZ[0][0]);
                accZ[0][1] = MFMA16(a0, z1, accZ[0][1]);
                accZ[1][0] = MFMA16(a1, z0, accZ[1][0]);
                accZ[1][1] = MFMA16(a1, z1, accZ[1][1]);
                if (s < nX) {
                    accI[0][0] = MFMA16(a0, q0, accI[0][0]);
                    accI[0][1] = MFMA16(a0, q1, accI[0][1]);
                    accI[1][0] = MFMA16(a1, q0, accI[1][0]);
                    accI[1][1] = MFMA16(a1, q1, accI[1][1]);
                } else {
                    accN[0][0] = MFMA16(a0, q0, accN[0][0]);
                    accN[0][1] = MFMA16(a0, q1, accN[0][1]);
                    accN[1][0] = MFMA16(a1, q0, accN[1][0]);
                    accN[1][1] = MFMA16(a1, q1, accN[1][1]);
                }
                __syncthreads();
            }

            // cross-group reduction: group1 -> LDS, group0 adds + epilogue
            float* red = (float*)&lds[0][0][0];   // 16384 floats = 64 KiB
            if (g == 1) {
#pragma unroll
                for (int m = 0; m < 2; ++m)
#pragma unroll
                    for (int n = 0; n < 2; ++n) {
                        int mn = (m << 1) | n;
                        *(f32x4*)&red[((((quad << 2) + 0) << 2 | mn) * 64 + lane) << 2] = accR[m][n];
                        *(f32x4*)&red[((((quad << 2) + 1) << 2 | mn) * 64 + lane) << 2] = accZ[m][n];
                        *(f32x4*)&red[((((quad << 2) + 2) << 2 | mn) * 64 + lane) << 2] = accI[m][n];
                        *(f32x4*)&red[((((quad << 2) + 3) << 2 | mn) * 64 + lane) << 2] = accN[m][n];
                    }
            }
            __syncthreads();
            if (g == 0) {
#pragma unroll
                for (int m = 0; m < 2; ++m)
#pragma unroll
                    for (int n = 0; n < 2; ++n) {
                        int mn = (m << 1) | n;
                        accR[m][n] += *(const f32x4*)&red[((((quad << 2) + 0) << 2 | mn) * 64 + lane) << 2];
                        accZ[m][n] += *(const f32x4*)&red[((((quad << 2) + 1) << 2 | mn) * 64 + lane) << 2];
                        accI[m][n] += *(const f32x4*)&red[((((quad << 2) + 2) << 2 | mn) * 64 + lane) << 2];
                        accN[m][n] += *(const f32x4*)&red[((((quad << 2) + 3) << 2 | mn) * 64 + lane) << 2];
                        int j = j0 + wc + 16 * n + fr;
                        float b_r = bi[j] + bh[j];
                        float b_z = bi[H_ + j] + bh[H_ + j];
                        float b_i = bi[2 * H_ + j];
                        float b_h = bh[2 * H_ + j];
#pragma unroll
                        for (int i = 0; i < 4; ++i) {
                            int brow = b0 + wr + 16 * m + kc * 4 + i;
                            float rv = 1.f / (1.f + __expf(-(accR[m][n][i] + b_r)));
                            float zv = 1.f / (1.f + __expf(-(accZ[m][n][i] + b_z)));
                            float nv = tanhf(accI[m][n][i] + b_i + rv * (accN[m][n][i] + b_h));
                            float hp = Hpf[(size_t)brow * H_ + j];
                            float hn = (1.f - zv) * nv + zv * hp;
                            hob[(size_t)brow * H_ + j] = f2b(hn);
                            hof[(size_t)brow * H_ + j] = hn;
                        }
                    }
            }
            __syncthreads();
        }
        grid.sync();
    }
}

// ---------------- per-step linear head ----------------

__global__ __launch_bounds__(256) void k_linear(const u16* __restrict__ h2all,
                                                const u16* __restrict__ wT,
                                                const float* __restrict__ lb,
                                                float* __restrict__ out) {
    int bid = blockIdx.x;
    int t = bid >> 5;                 // 32 tiles per t
    int tile = bid & 31;
    int b0 = (tile >> 3) << 6;        // 4 b-tiles
    int o0 = (tile & 7) << 6;         // 8 o-tiles
    const u16* A = h2all + (size_t)(t + 1) * BH_;
    const u16* W = wT + (size_t)t * (O_ * H_);

    __shared__ u16 lds[2][2][64 * 32];
    int tid = threadIdx.x;
    int srow = tid >> 2;
    int ssoff = ((tid & 3) ^ ((srow >> 1) & 3)) << 3;
    int wid = tid >> 6, lane = tid & 63;
    int wr = ((wid >> 1) << 5), wc = ((wid & 1) << 5);
    int fr = lane & 15, kc = lane >> 4;
    int aoff[2], boff[2];
#pragma unroll
    for (int m = 0; m < 2; ++m) {
        int rr = wr + 16 * m + fr;
        aoff[m] = rr * 32 + ((kc ^ ((rr >> 1) & 3)) << 3);
    }
#pragma unroll
    for (int n = 0; n < 2; ++n) {
        int cc = wc + 16 * n + fr;
        boff[n] = cc * 32 + ((kc ^ ((cc >> 1) & 3)) << 3);
    }
    f32x4 acc[2][2] = {};

    gl_lds16(A + (size_t)(b0 + srow) * H_ + ssoff, &lds[0][0][tid << 3]);
    gl_lds16(W + (size_t)(o0 + srow) * H_ + ssoff, &lds[0][1][tid << 3]);
    __syncthreads();
    for (int it = 0; it < 32; ++it) {
        int cur = it & 1;
        if (it + 1 < 32) {
            int kk = (it + 1) << 5;
            gl_lds16(A + (size_t)(b0 + srow) * H_ + kk + ssoff, &lds[cur ^ 1][0][tid << 3]);
            gl_lds16(W + (size_t)(o0 + srow) * H_ + kk + ssoff, &lds[cur ^ 1][1][tid << 3]);
        }
        bf16x8 a0 = *(const bf16x8*)&lds[cur][0][aoff[0]];
        bf16x8 a1 = *(const bf16x8*)&lds[cur][0][aoff[1]];
        bf16x8 w0 = *(const bf16x8*)&lds[cur][1][boff[0]];
        bf16x8 w1 = *(const bf16x8*)&lds[cur][1][boff[1]];
        acc[0][0] = MFMA16(a0, w0, acc[0][0]);
        acc[0][1] = MFMA16(a0, w1, acc[0][1]);
        acc[1][0] = MFMA16(a1, w0, acc[1][0]);
        acc[1][1] = MFMA16(a1, w1, acc[1][1]);
        __syncthreads();
    }
#pragma unroll
    for (int m = 0; m < 2; ++m)
#pragma unroll
        for (int n = 0; n < 2; ++n) {
            int o = o0 + wc + 16 * n + fr;
            float bb = lb[t * O_ + o];
#pragma unroll
            for (int i = 0; i < 4; ++i) {
                int b = b0 + wr + 16 * m + kc * 4 + i;
                out[((size_t)b * S_ + t) * O_ + o] = acc[m][n][i] + bb;
            }
        }
}

// ---------------- final hidden-state outputs ----------------

__global__ void k_finals(const float* __restrict__ h0f, const float* __restrict__ h1f,
                         const float* __restrict__ h2f, float* __restrict__ out) {
    int i = blockIdx.x * blockDim.x + threadIdx.x;     // 3*BH_
    int c = i / BH_, r = i - c * BH_;
    // t=63 -> slot 63&1 = 1
    const float* s = (c == 0) ? (h0f + BH_) : (c == 1) ? (h1f + BH_) : (h2f + BH_);
    out[(size_t)B_ * S_ * O_ + (size_t)c * BH_ + r] = s[r];
}

// ---------------- launch ----------------

extern "C" void kernel_launch(void* const* d_in, const int* in_sizes, int n_in,
                              void* d_out, int out_size, void* d_ws, size_t ws_size,
                              hipStream_t stream) {
    (void)in_sizes; (void)n_in; (void)out_size; (void)ws_size;
    const float* x   = (const float*)d_in[0];
    const float* wi0 = (const float*)d_in[1];
    const float* wh0 = (const float*)d_in[2];
    const float* bi0 = (const float*)d_in[3];
    const float* bh0 = (const float*)d_in[4];
    const float* wi1 = (const float*)d_in[5];
    const float* wh1 = (const float*)d_in[6];
    const float* bi1 = (const float*)d_in[7];
    const float* bh1 = (const float*)d_in[8];
    const float* wi2 = (const float*)d_in[9];
    const float* wh2 = (const float*)d_in[10];
    const float* bi2 = (const float*)d_in[11];
    const float* bh2 = (const float*)d_in[12];
    const float* lw  = (const float*)d_in[13];
    const float* lb  = (const float*)d_in[14];

    char* base = (char*)d_ws;
    size_t off = 0;
    auto alloc = [&](size_t bytes) {
        char* p = base + off;
        off = (off + bytes + 255) & ~(size_t)255;
        return p;
    };
    u16* Xb  = (u16*)alloc((size_t)B_ * S_ * D_ * 2);
    u16* Wi0 = (u16*)alloc((size_t)G_ * D_ * 2);
    u16* Wh0 = (u16*)alloc((size_t)G_ * H_ * 2);
    u16* Wi1 = (u16*)alloc((size_t)G_ * H_ * 2);
    u16* Wh1 = (u16*)alloc((size_t)G_ * H_ * 2);
    u16* Wi2 = (u16*)alloc((size_t)G_ * H_ * 2);
    u16* Wh2 = (u16*)alloc((size_t)G_ * H_ * 2);
    u16* h0b = (u16*)alloc((size_t)2 * BH_ * 2);
    u16* h1b = (u16*)alloc((size_t)2 * BH_ * 2);
    u16* h2a = (u16*)alloc((size_t)(S_ + 1) * BH_ * 2);
    float* h0f = (float*)alloc((size_t)2 * BH_ * 4);
    float* h1f = (float*)alloc((size_t)2 * BH_ * 4);
    float* h2f = (float*)alloc((size_t)2 * BH_ * 4);
    u16* WLt = (u16*)alloc((size_t)S_ * O_ * H_ * 2);

    k_conv<<<1024, 256, 0, stream>>>(x,   Xb,  (B_ * S_ * D_) / 4);
    k_conv<<<1024, 256, 0, stream>>>(wi0, Wi0, (G_ * D_) / 4);
    k_conv<<<1024, 256, 0, stream>>>(wh0, Wh0, (G_ * H_) / 4);
    k_conv<<<1024, 256, 0, stream>>>(wi1, Wi1, (G_ * H_) / 4);
    k_conv<<<1024, 256, 0, stream>>>(wh1, Wh1, (G_ * H_) / 4);
    k_conv<<<1024, 256, 0, stream>>>(wi2, Wi2, (G_ * H_) / 4);
    k_conv<<<1024, 256, 0, stream>>>(wh2, Wh2, (G_ * H_) / 4);
    k_twl<<<S_ * 512, 256, 0, stream>>>(lw, WLt);
    hipMemsetAsync(h0b, 0, (size_t)2 * BH_ * 2, stream);
    hipMemsetAsync(h1b, 0, (size_t)2 * BH_ * 2, stream);
    hipMemsetAsync(h2a, 0, (size_t)BH_ * 2, stream);          // slot 0 = t=-1
    hipMemsetAsync(h0f, 0, (size_t)2 * BH_ * 4, stream);
    hipMemsetAsync(h1f, 0, (size_t)2 * BH_ * 4, stream);
    hipMemsetAsync(h2f, 0, (size_t)2 * BH_ * 4, stream);

    GruArgs ga;
    ga.Xb = Xb;
    ga.Wi0 = Wi0; ga.Wh0 = Wh0; ga.Wi1 = Wi1; ga.Wh1 = Wh1; ga.Wi2 = Wi2; ga.Wh2 = Wh2;
    ga.bi0 = bi0; ga.bh0 = bh0; ga.bi1 = bi1; ga.bh1 = bh1; ga.bi2 = bi2; ga.bh2 = bh2;
    ga.h0b = h0b; ga.h1b = h1b; ga.h2a = h2a;
    ga.h0f = h0f; ga.h1f = h1f; ga.h2f = h2f;

    void* args[] = {&ga};
    hipLaunchCooperativeKernel((void*)k_gru, dim3(192), dim3(512), args, 0, stream);

    k_linear<<<S_ * 32, 256, 0, stream>>>(h2a, WLt, lb, (float*)d_out);
    k_finals<<<(3 * BH_) / 256, 256, 0, stream>>>(h0f, h1f, h2f, (float*)d_out);
}

// Round 3
// 3341.708 us; speedup vs baseline: 1.0052x; 1.0052x over previous
//
#include <hip/hip_runtime.h>
#include <hip/hip_bf16.h>
#include <hip/hip_cooperative_groups.h>
#include <stdint.h>

namespace cg = cooperative_groups;

#define B_ 256
#define S_ 64
#define D_ 256
#define H_ 1024
#define O_ 512
#define G_ 3072          // 3*H
#define BH_ (B_ * H_)    // 262144

typedef unsigned short u16;
typedef __attribute__((ext_vector_type(8))) short bf16x8;
typedef __attribute__((ext_vector_type(4))) float f32x4;

#define MFMA16(a, b, c) __builtin_amdgcn_mfma_f32_16x16x32_bf16((a), (b), (c), 0, 0, 0)

__device__ __forceinline__ u16 f2b(float f) {
    union { float f; uint32_t u; } v; v.f = f;
    uint32_t u = v.u;
    uint32_t r = (u + 0x7fffu + ((u >> 16) & 1u)) >> 16;   // RNE
    return (u16)r;
}

__device__ __forceinline__ void gl_lds16(const u16* g, u16* l) {
    __builtin_amdgcn_global_load_lds(
        (const __attribute__((address_space(1))) unsigned int*)g,
        (__attribute__((address_space(3))) unsigned int*)l, 16, 0, 0);
}

// ---------------- prep kernels ----------------

__global__ void k_conv(const float* __restrict__ s, u16* __restrict__ d, int n4) {
    int i = blockIdx.x * blockDim.x + threadIdx.x;
    int st = gridDim.x * blockDim.x;
    for (; i < n4; i += st) {
        float4 v = ((const float4*)s)[i];
        ushort4 o;
        o.x = f2b(v.x); o.y = f2b(v.y); o.z = f2b(v.z); o.w = f2b(v.w);
        ((ushort4*)d)[i] = o;
    }
}

// lin_w [S][H][O] f32 -> [S][O][H] bf16
__global__ __launch_bounds__(256) void k_twl(const float* __restrict__ w, u16* __restrict__ o) {
    __shared__ float tile[32][33];
    int bid = blockIdx.x;
    int t = bid >> 9;            // 512 tiles / t  (32 j-tiles x 16 o-tiles)
    int rem = bid & 511;
    int j0 = (rem >> 4) << 5;
    int o0 = (rem & 15) << 5;
    int tx = threadIdx.x & 31, ty = threadIdx.x >> 5;
    const float* base = w + (size_t)t * (H_ * O_);
#pragma unroll
    for (int i = 0; i < 4; ++i) {
        int r = ty + (i << 3);
        tile[r][tx] = base[(size_t)(j0 + r) * O_ + o0 + tx];
    }
    __syncthreads();
    u16* ob = o + (size_t)t * (O_ * H_);
#pragma unroll
    for (int i = 0; i < 4; ++i) {
        int r = ty + (i << 3);
        ob[(size_t)(o0 + r) * H_ + j0 + tx] = f2b(tile[tx][r]);
    }
}

// ---------------- persistent cooperative GRU ----------------

struct GruArgs {
    const u16* Xb;
    const u16 *Wi0, *Wh0, *Wi1, *Wh1, *Wi2, *Wh2;
    const float *bi0, *bh0, *bi1, *bh1, *bi2, *bh2;
    u16 *h0b, *h1b, *h2a;        // bf16 state (h2a: 65 slots, slot t+1 = time t)
    float *h0f, *h1f, *h2f;      // fp32 state (double-buffered)
};

__global__ __launch_bounds__(512, 2) void k_gru(GruArgs p) {
    // XCD-affinity mapping: wg%8 -> XCD.  Per XCD: 3 cells x 2 j-tiles x 4 b-tiles.
    int w = blockIdx.x;
    int xcd = w & 7;
    int q = w >> 3;              // 0..23
    int cell = q >> 3;           // 0..2
    int r = q & 7;
    int j0 = ((xcd << 1) + (r >> 2)) << 6;   // 16 j-tiles of 64
    int b0 = (r & 3) << 6;                   // 4 b-tiles of 64

    const u16 *Wi, *Wh;
    const float *bi, *bh;
    int K0;
    if (cell == 0)      { Wi = p.Wi0; Wh = p.Wh0; bi = p.bi0; bh = p.bh0; K0 = D_; }
    else if (cell == 1) { Wi = p.Wi1; Wh = p.Wh1; bi = p.bi1; bh = p.bh1; K0 = H_; }
    else                { Wi = p.Wi2; Wh = p.Wh2; bi = p.bi2; bh = p.bh2; K0 = H_; }
    const int nX = K0 >> 6;
    const int nSup = nX + (H_ >> 6);

    __shared__ u16 lds[2][4][64 * 64];   // [dbuf][A,Wr,Wz,Wn][64 rows x 64 k] = 64 KiB

    int tid = threadIdx.x;
    int srow = tid >> 3;                           // staging row 0..63
    int soff = ((tid & 7) ^ (srow & 7)) << 3;      // swizzled 16B chunk (elems)

    int wid = tid >> 6, lane = tid & 63;
    int g = wid >> 2;                              // K-half group (0/1)
    int quad = wid & 3;
    int wr = (quad >> 1) << 5, wc = (quad & 1) << 5;
    int fr = lane & 15, kc = lane >> 4;

    int aoff[2], boff[2];
#pragma unroll
    for (int m = 0; m < 2; ++m) {
        int row = wr + 16 * m + fr;
        aoff[m] = row * 64 + ((((g << 2) + kc) ^ (row & 7)) << 3);
    }
#pragma unroll
    for (int n = 0; n < 2; ++n) {
        int col = wc + 16 * n + fr;
        boff[n] = col * 64 + ((((g << 2) + kc) ^ (col & 7)) << 3);
    }

    cg::grid_group grid = cg::this_grid();

    for (int k = 0; k < S_ + 2; ++k) {
        int t = k - cell;
        if (t >= 0 && t < S_) {
            const u16* Ax; int ldax;
            const u16* Ah;
            const float* Hpf;
            u16* hob; float* hof;
            if (cell == 0) {
                Ax = p.Xb + (size_t)b0 * (S_ * D_) + t * D_; ldax = S_ * D_;
                Ah  = p.h0b + ((t + 1) & 1) * BH_ + (size_t)b0 * H_;
                Hpf = p.h0f + ((t + 1) & 1) * BH_;
                hob = p.h0b + (t & 1) * BH_;
                hof = p.h0f + (t & 1) * BH_;
            } else if (cell == 1) {
                Ax = p.h0b + (t & 1) * BH_ + (size_t)b0 * H_; ldax = H_;
                Ah  = p.h1b + ((t + 1) & 1) * BH_ + (size_t)b0 * H_;
                Hpf = p.h1f + ((t + 1) & 1) * BH_;
                hob = p.h1b + (t & 1) * BH_;
                hof = p.h1f + (t & 1) * BH_;
            } else {
                Ax = p.h1b + (t & 1) * BH_ + (size_t)b0 * H_; ldax = H_;
                Ah  = p.h2a + (size_t)t * BH_ + (size_t)b0 * H_;
                Hpf = p.h2f + ((t + 1) & 1) * BH_;
                hob = p.h2a + (size_t)(t + 1) * BH_;
                hof = p.h2f + (t & 1) * BH_;
            }

            auto stage = [&](int s, int nb) {
                const u16 *arow, *wrow; size_t gs;
                if (s < nX) {
                    int kk = s << 6;
                    arow = Ax + (size_t)srow * ldax + kk + soff;
                    wrow = Wi + (size_t)(j0 + srow) * K0 + kk + soff;
                    gs = (size_t)H_ * K0;
                } else {
                    int kk = (s - nX) << 6;
                    arow = Ah + (size_t)srow * H_ + kk + soff;
                    wrow = Wh + (size_t)(j0 + srow) * H_ + kk + soff;
                    gs = (size_t)H_ * H_;
                }
                gl_lds16(arow,          &lds[nb][0][tid << 3]);
                gl_lds16(wrow,          &lds[nb][1][tid << 3]);
                gl_lds16(wrow + gs,     &lds[nb][2][tid << 3]);
                gl_lds16(wrow + 2 * gs, &lds[nb][3][tid << 3]);
            };

            f32x4 accR[2][2] = {}, accZ[2][2] = {}, accI[2][2] = {}, accN[2][2] = {};

            stage(0, 0);
            __syncthreads();

            for (int s = 0; s < nSup; ++s) {
                int cur = s & 1;
                if (s + 1 < nSup) stage(s + 1, cur ^ 1);

                bf16x8 a0 = *(const bf16x8*)&lds[cur][0][aoff[0]];
                bf16x8 a1 = *(const bf16x8*)&lds[cur][0][aoff[1]];
                bf16x8 r0 = *(const bf16x8*)&lds[cur][1][boff[0]];
                bf16x8 r1 = *(const bf16x8*)&lds[cur][1][boff[1]];
                bf16x8 z0 = *(const bf16x8*)&lds[cur][2][boff[0]];
                bf16x8 z1 = *(const bf16x8*)&lds[cur][2][boff[1]];
                bf16x8 q0 = *(const bf16x8*)&lds[cur][3][boff[0]];
                bf16x8 q1 = *(const bf16x8*)&lds[cur][3][boff[1]];

                accR[0][0] = MFMA16(a0, r0, accR[0][0]);
                accR[0][1] = MFMA16(a0, r1, accR[0][1]);
                accR[1][0] = MFMA16(a1, r0, accR[1][0]);
                accR[1][1] = MFMA16(a1, r1, accR[1][1]);
                accZ[0][0] = MFMA16(a0, z0, accZ[0][0]);
                accZ[0][1] = MFMA16(a0, z1, accZ[0][1]);
                accZ[1][0] = MFMA16(a1, z0, accZ[1][0]);
                accZ[1][1] = MFMA16(a1, z1, accZ[1][1]);
                if (s < nX) {
                    accI[0][0] = MFMA16(a0, q0, accI[0][0]);
                    accI[0][1] = MFMA16(a0, q1, accI[0][1]);
                    accI[1][0] = MFMA16(a1, q0, accI[1][0]);
                    accI[1][1] = MFMA16(a1, q1, accI[1][1]);
                } else {
                    accN[0][0] = MFMA16(a0, q0, accN[0][0]);
                    accN[0][1] = MFMA16(a0, q1, accN[0][1]);
                    accN[1][0] = MFMA16(a1, q0, accN[1][0]);
                    accN[1][1] = MFMA16(a1, q1, accN[1][1]);
                }
                __syncthreads();
            }

            // cross-group reduction: group1 -> LDS, group0 adds + epilogue
            float* red = (float*)&lds[0][0][0];   // 16384 floats = 64 KiB
            if (g == 1) {
#pragma unroll
                for (int m = 0; m < 2; ++m)
#pragma unroll
                    for (int n = 0; n < 2; ++n) {
                        int mn = (m << 1) | n;
                        *(f32x4*)&red[((((quad << 2) + 0) << 2 | mn) * 64 + lane) << 2] = accR[m][n];
                        *(f32x4*)&red[((((quad << 2) + 1) << 2 | mn) * 64 + lane) << 2] = accZ[m][n];
                        *(f32x4*)&red[((((quad << 2) + 2) << 2 | mn) * 64 + lane) << 2] = accI[m][n];
                        *(f32x4*)&red[((((quad << 2) + 3) << 2 | mn) * 64 + lane) << 2] = accN[m][n];
                    }
            }
            __syncthreads();
            if (g == 0) {
#pragma unroll
                for (int m = 0; m < 2; ++m)
#pragma unroll
                    for (int n = 0; n < 2; ++n) {
                        int mn = (m << 1) | n;
                        accR[m][n] += *(const f32x4*)&red[((((quad << 2) + 0) << 2 | mn) * 64 + lane) << 2];
                        accZ[m][n] += *(const f32x4*)&red[((((quad << 2) + 1) << 2 | mn) * 64 + lane) << 2];
                        accI[m][n] += *(const f32x4*)&red[((((quad << 2) + 2) << 2 | mn) * 64 + lane) << 2];
                        accN[m][n] += *(const f32x4*)&red[((((quad << 2) + 3) << 2 | mn) * 64 + lane) << 2];
                        int j = j0 + wc + 16 * n + fr;
                        float b_r = bi[j] + bh[j];
                        float b_z = bi[H_ + j] + bh[H_ + j];
                        float b_i = bi[2 * H_ + j];
                        float b_h = bh[2 * H_ + j];
#pragma unroll
                        for (int i = 0; i < 4; ++i) {
                            int brow = b0 + wr + 16 * m + kc * 4 + i;
                            float rv = 1.f / (1.f + __expf(-(accR[m][n][i] + b_r)));
                            float zv = 1.f / (1.f + __expf(-(accZ[m][n][i] + b_z)));
                            float nv = tanhf(accI[m][n][i] + b_i + rv * (accN[m][n][i] + b_h));
                            float hp = Hpf[(size_t)brow * H_ + j];
                            float hn = (1.f - zv) * nv + zv * hp;
                            hob[(size_t)brow * H_ + j] = f2b(hn);
                            hof[(size_t)brow * H_ + j] = hn;
                        }
                    }
            }
            __syncthreads();
        }
        grid.sync();
    }
}

// ---------------- per-step linear head ----------------

__global__ __launch_bounds__(256) void k_linear(const u16* __restrict__ h2all,
                                                const u16* __restrict__ wT,
                                                const float* __restrict__ lb,
                                                float* __restrict__ out) {
    int bid = blockIdx.x;
    int t = bid >> 5;                 // 32 tiles per t
    int tile = bid & 31;
    int b0 = (tile >> 3) << 6;        // 4 b-tiles
    int o0 = (tile & 7) << 6;         // 8 o-tiles
    const u16* A = h2all + (size_t)(t + 1) * BH_;
    const u16* W = wT + (size_t)t * (O_ * H_);

    __shared__ u16 lds[2][2][64 * 32];
    int tid = threadIdx.x;
    int srow = tid >> 2;
    int ssoff = ((tid & 3) ^ ((srow >> 1) & 3)) << 3;
    int wid = tid >> 6, lane = tid & 63;
    int wr = ((wid >> 1) << 5), wc = ((wid & 1) << 5);
    int fr = lane & 15, kc = lane >> 4;
    int aoff[2], boff[2];
#pragma unroll
    for (int m = 0; m < 2; ++m) {
        int rr = wr + 16 * m + fr;
        aoff[m] = rr * 32 + ((kc ^ ((rr >> 1) & 3)) << 3);
    }
#pragma unroll
    for (int n = 0; n < 2; ++n) {
        int cc = wc + 16 * n + fr;
        boff[n] = cc * 32 + ((kc ^ ((cc >> 1) & 3)) << 3);
    }
    f32x4 acc[2][2] = {};

    gl_lds16(A + (size_t)(b0 + srow) * H_ + ssoff, &lds[0][0][tid << 3]);
    gl_lds16(W + (size_t)(o0 + srow) * H_ + ssoff, &lds[0][1][tid << 3]);
    __syncthreads();
    for (int it = 0; it < 32; ++it) {
        int cur = it & 1;
        if (it + 1 < 32) {
            int kk = (it + 1) << 5;
            gl_lds16(A + (size_t)(b0 + srow) * H_ + kk + ssoff, &lds[cur ^ 1][0][tid << 3]);
            gl_lds16(W + (size_t)(o0 + srow) * H_ + kk + ssoff, &lds[cur ^ 1][1][tid << 3]);
        }
        bf16x8 a0 = *(const bf16x8*)&lds[cur][0][aoff[0]];
        bf16x8 a1 = *(const bf16x8*)&lds[cur][0][aoff[1]];
        bf16x8 w0 = *(const bf16x8*)&lds[cur][1][boff[0]];
        bf16x8 w1 = *(const bf16x8*)&lds[cur][1][boff[1]];
        acc[0][0] = MFMA16(a0, w0, acc[0][0]);
        acc[0][1] = MFMA16(a0, w1, acc[0][1]);
        acc[1][0] = MFMA16(a1, w0, acc[1][0]);
        acc[1][1] = MFMA16(a1, w1, acc[1][1]);
        __syncthreads();
    }
#pragma unroll
    for (int m = 0; m < 2; ++m)
#pragma unroll
        for (int n = 0; n < 2; ++n) {
            int o = o0 + wc + 16 * n + fr;
            float bb = lb[t * O_ + o];
#pragma unroll
            for (int i = 0; i < 4; ++i) {
                int b = b0 + wr + 16 * m + kc * 4 + i;
                out[((size_t)b * S_ + t) * O_ + o] = acc[m][n][i] + bb;
            }
        }
}

// ---------------- final hidden-state outputs ----------------

__global__ void k_finals(const float* __restrict__ h0f, const float* __restrict__ h1f,
                         const float* __restrict__ h2f, float* __restrict__ out) {
    int i = blockIdx.x * blockDim.x + threadIdx.x;     // 3*BH_
    int c = i / BH_, r = i - c * BH_;
    // t=63 -> slot 63&1 = 1
    const float* s = (c == 0) ? (h0f + BH_) : (c == 1) ? (h1f + BH_) : (h2f + BH_);
    out[(size_t)B_ * S_ * O_ + (size_t)c * BH_ + r] = s[r];
}

// ---------------- launch ----------------

extern "C" void kernel_launch(void* const* d_in, const int* in_sizes, int n_in,
                              void* d_out, int out_size, void* d_ws, size_t ws_size,
                              hipStream_t stream) {
    (void)in_sizes; (void)n_in; (void)out_size; (void)ws_size;
    const float* x   = (const float*)d_in[0];
    const float* wi0 = (const float*)d_in[1];
    const float* wh0 = (const float*)d_in[2];
    const float* bi0 = (const float*)d_in[3];
    const float* bh0 = (const float*)d_in[4];
    const float* wi1 = (const float*)d_in[5];
    const float* wh1 = (const float*)d_in[6];
    const float* bi1 = (const float*)d_in[7];
    const float* bh1 = (const float*)d_in[8];
    const float* wi2 = (const float*)d_in[9];
    const float* wh2 = (const float*)d_in[10];
    const float* bi2 = (const float*)d_in[11];
    const float* bh2 = (const float*)d_in[12];
    const float* lw  = (const float*)d_in[13];
    const float* lb  = (const float*)d_in[14];

    char* base = (char*)d_ws;
    size_t off = 0;
    auto alloc = [&](size_t bytes) {
        char* p = base + off;
        off = (off + bytes + 255) & ~(size_t)255;
        return p;
    };
    u16* Xb  = (u16*)alloc((size_t)B_ * S_ * D_ * 2);
    u16* Wi0 = (u16*)alloc((size_t)G_ * D_ * 2);
    u16* Wh0 = (u16*)alloc((size_t)G_ * H_ * 2);
    u16* Wi1 = (u16*)alloc((size_t)G_ * H_ * 2);
    u16* Wh1 = (u16*)alloc((size_t)G_ * H_ * 2);
    u16* Wi2 = (u16*)alloc((size_t)G_ * H_ * 2);
    u16* Wh2 = (u16*)alloc((size_t)G_ * H_ * 2);
    u16* h0b = (u16*)alloc((size_t)2 * BH_ * 2);
    u16* h1b = (u16*)alloc((size_t)2 * BH_ * 2);
    u16* h2a = (u16*)alloc((size_t)(S_ + 1) * BH_ * 2);
    float* h0f = (float*)alloc((size_t)2 * BH_ * 4);
    float* h1f = (float*)alloc((size_t)2 * BH_ * 4);
    float* h2f = (float*)alloc((size_t)2 * BH_ * 4);
    u16* WLt = (u16*)alloc((size_t)S_ * O_ * H_ * 2);

    k_conv<<<1024, 256, 0, stream>>>(x,   Xb,  (B_ * S_ * D_) / 4);
    k_conv<<<1024, 256, 0, stream>>>(wi0, Wi0, (G_ * D_) / 4);
    k_conv<<<1024, 256, 0, stream>>>(wh0, Wh0, (G_ * H_) / 4);
    k_conv<<<1024, 256, 0, stream>>>(wi1, Wi1, (G_ * H_) / 4);
    k_conv<<<1024, 256, 0, stream>>>(wh1, Wh1, (G_ * H_) / 4);
    k_conv<<<1024, 256, 0, stream>>>(wi2, Wi2, (G_ * H_) / 4);
    k_conv<<<1024, 256, 0, stream>>>(wh2, Wh2, (G_ * H_) / 4);
    k_twl<<<S_ * 512, 256, 0, stream>>>(lw, WLt);
    hipMemsetAsync(h0b, 0, (size_t)2 * BH_ * 2, stream);
    hipMemsetAsync(h1b, 0, (size_t)2 * BH_ * 2, stream);
    hipMemsetAsync(h2a, 0, (size_t)BH_ * 2, stream);          // slot 0 = t=-1
    hipMemsetAsync(h0f, 0, (size_t)2 * BH_ * 4, stream);
    hipMemsetAsync(h1f, 0, (size_t)2 * BH_ * 4, stream);
    hipMemsetAsync(h2f, 0, (size_t)2 * BH_ * 4, stream);

    GruArgs ga;
    ga.Xb = Xb;
    ga.Wi0 = Wi0; ga.Wh0 = Wh0; ga.Wi1 = Wi1; ga.Wh1 = Wh1; ga.Wi2 = Wi2; ga.Wh2 = Wh2;
    ga.bi0 = bi0; ga.bh0 = bh0; ga.bi1 = bi1; ga.bh1 = bh1; ga.bi2 = bi2; ga.bh2 = bh2;
    ga.h0b = h0b; ga.h1b = h1b; ga.h2a = h2a;
    ga.h0f = h0f; ga.h1f = h1f; ga.h2f = h2f;

    void* args[] = {&ga};
    hipLaunchCooperativeKernel((void*)k_gru, dim3(192), dim3(512), args, 0, stream);

    k_linear<<<S_ * 32, 256, 0, stream>>>(h2a, WLt, lb, (float*)d_out);
    k_finals<<<(3 * BH_) / 256, 256, 0, stream>>>(h0f, h1f, h2f, (float*)d_out);
}

// Round 4
// 3339.028 us; speedup vs baseline: 1.0060x; 1.0008x over previous
//
#include <hip/hip_runtime.h>
#include <hip/hip_bf16.h>
#include <hip/hip_cooperative_groups.h>
#include <stdint.h>

namespace cg = cooperative_groups;

#define B_ 256
#define S_ 64
#define D_ 256
#define H_ 1024
#define O_ 512
#define G_ 3072          // 3*H
#define BH_ (B_ * H_)    // 262144

typedef unsigned short u16;
typedef __attribute__((ext_vector_type(8))) short bf16x8;
typedef __attribute__((ext_vector_type(4))) float f32x4;

#define MFMA16(a, b, c) __builtin_amdgcn_mfma_f32_16x16x32_bf16((a), (b), (c), 0, 0, 0)

__device__ __forceinline__ u16 f2b(float f) {
    union { float f; uint32_t u; } v; v.f = f;
    uint32_t u = v.u;
    uint32_t r = (u + 0x7fffu + ((u >> 16) & 1u)) >> 16;   // RNE
    return (u16)r;
}

__device__ __forceinline__ void gl_lds16(const u16* g, u16* l) {
    __builtin_amdgcn_global_load_lds(
        (const __attribute__((address_space(1))) unsigned int*)g,
        (__attribute__((address_space(3))) unsigned int*)l, 16, 0, 0);
}

// ---------------- prep kernels ----------------

__global__ void k_conv(const float* __restrict__ s, u16* __restrict__ d, int n4) {
    int i = blockIdx.x * blockDim.x + threadIdx.x;
    int st = gridDim.x * blockDim.x;
    for (; i < n4; i += st) {
        float4 v = ((const float4*)s)[i];
        ushort4 o;
        o.x = f2b(v.x); o.y = f2b(v.y); o.z = f2b(v.z); o.w = f2b(v.w);
        ((ushort4*)d)[i] = o;
    }
}

// lin_w [S][H][O] f32 -> [S][O][H] bf16
__global__ __launch_bounds__(256) void k_twl(const float* __restrict__ w, u16* __restrict__ o) {
    __shared__ float tile[32][33];
    int bid = blockIdx.x;
    int t = bid >> 9;            // 512 tiles / t  (32 j-tiles x 16 o-tiles)
    int rem = bid & 511;
    int j0 = (rem >> 4) << 5;
    int o0 = (rem & 15) << 5;
    int tx = threadIdx.x & 31, ty = threadIdx.x >> 5;
    const float* base = w + (size_t)t * (H_ * O_);
#pragma unroll
    for (int i = 0; i < 4; ++i) {
        int r = ty + (i << 3);
        tile[r][tx] = base[(size_t)(j0 + r) * O_ + o0 + tx];
    }
    __syncthreads();
    u16* ob = o + (size_t)t * (O_ * H_);
#pragma unroll
    for (int i = 0; i < 4; ++i) {
        int r = ty + (i << 3);
        ob[(size_t)(o0 + r) * H_ + j0 + tx] = f2b(tile[tx][r]);
    }
}

// ---------------- persistent cooperative GRU + linear head ----------------

struct GruArgs {
    const u16* Xb;
    const u16 *Wi0, *Wh0, *Wi1, *Wh1, *Wi2, *Wh2;
    const float *bi0, *bh0, *bi1, *bh1, *bi2, *bh2;
    u16 *h0b, *h1b, *h2a;        // bf16 state (h2a: 65 slots, slot t+1 = time t)
    float *h0f, *h1f, *h2f;      // fp32 state (double-buffered)
    const u16* WLt;              // [S][O][H] bf16
    const float* lb;             // [S][O]
    float* out;                  // [B][S][O]
};

__global__ __launch_bounds__(512, 2) void k_gru(GruArgs p) {
    // XCD-affinity: wg%8 -> XCD. Per XCD: 3 GRU cells x (2 j-slices x 4 b) + linear x 4 b.
    int w = blockIdx.x;
    int xcd = w & 7;
    int q = w >> 3;              // 0..27
    int cell, j0 = 0, b0, o0 = 0;
    if (q < 24) {
        cell = q >> 3;           // 0..2
        int r = q & 7;
        j0 = ((xcd << 1) + (r >> 2)) << 6;   // 16 j-tiles of 64
        b0 = (r & 3) << 6;
    } else {
        cell = 3;                // linear head
        o0 = xcd << 6;           // 8 o-tiles of 64
        b0 = (q - 24) << 6;
    }

    const u16 *Wi = nullptr, *Wh = nullptr;
    const float *bi = nullptr, *bh = nullptr;
    int K0 = H_;
    if (cell == 0)      { Wi = p.Wi0; Wh = p.Wh0; bi = p.bi0; bh = p.bh0; K0 = D_; }
    else if (cell == 1) { Wi = p.Wi1; Wh = p.Wh1; bi = p.bi1; bh = p.bh1; }
    else if (cell == 2) { Wi = p.Wi2; Wh = p.Wh2; bi = p.bi2; bh = p.bh2; }
    const int nX = K0 >> 6;
    const int nSup = (cell == 3) ? (H_ >> 6) : nX + (H_ >> 6);

    __shared__ u16 lds[4][4][64 * 64];   // 4-deep dbuf x [A,Wr,Wz,Wn] x 8KB = 128 KiB

    int tid = threadIdx.x;
    int srow = tid >> 3;                           // staging row 0..63
    int soff = ((tid & 7) ^ (srow & 7)) << 3;      // swizzled 16B chunk (elems)

    int wid = tid >> 6, lane = tid & 63;
    int g = wid >> 2;                              // K-half group (0/1)
    int quad = wid & 3;
    int wr = (quad >> 1) << 5, wc = (quad & 1) << 5;
    int fr = lane & 15, kc = lane >> 4;

    int aoff[2], boff[2];
#pragma unroll
    for (int m = 0; m < 2; ++m) {
        int row = wr + 16 * m + fr;
        aoff[m] = row * 64 + ((((g << 2) + kc) ^ (row & 7)) << 3);
    }
#pragma unroll
    for (int n = 0; n < 2; ++n) {
        int col = wc + 16 * n + fr;
        boff[n] = col * 64 + ((((g << 2) + kc) ^ (col & 7)) << 3);
    }

    cg::grid_group grid = cg::this_grid();

    for (int k = 0; k < S_ + 3; ++k) {
        int t = k - cell;
        if (t >= 0 && t < S_) {
            if (cell < 3) {
                // ---------- GRU cell ----------
                const u16* Ax; int ldax;
                const u16* Ah;
                const float* Hpf;
                u16* hob; float* hof;
                if (cell == 0) {
                    Ax = p.Xb + (size_t)b0 * (S_ * D_) + t * D_; ldax = S_ * D_;
                    Ah  = p.h0b + ((t + 1) & 1) * BH_ + (size_t)b0 * H_;
                    Hpf = p.h0f + ((t + 1) & 1) * BH_;
                    hob = p.h0b + (t & 1) * BH_;
                    hof = p.h0f + (t & 1) * BH_;
                } else if (cell == 1) {
                    Ax = p.h0b + (t & 1) * BH_ + (size_t)b0 * H_; ldax = H_;
                    Ah  = p.h1b + ((t + 1) & 1) * BH_ + (size_t)b0 * H_;
                    Hpf = p.h1f + ((t + 1) & 1) * BH_;
                    hob = p.h1b + (t & 1) * BH_;
                    hof = p.h1f + (t & 1) * BH_;
                } else {
                    Ax = p.h1b + (t & 1) * BH_ + (size_t)b0 * H_; ldax = H_;
                    Ah  = p.h2a + (size_t)t * BH_ + (size_t)b0 * H_;
                    Hpf = p.h2f + ((t + 1) & 1) * BH_;
                    hob = p.h2a + (size_t)(t + 1) * BH_;
                    hof = p.h2f + (t & 1) * BH_;
                }

                auto stage = [&](int s, int nb) {
                    const u16 *arow, *wrow; size_t gs;
                    if (s < nX) {
                        int kk = s << 6;
                        arow = Ax + (size_t)srow * ldax + kk + soff;
                        wrow = Wi + (size_t)(j0 + srow) * K0 + kk + soff;
                        gs = (size_t)H_ * K0;
                    } else {
                        int kk = (s - nX) << 6;
                        arow = Ah + (size_t)srow * H_ + kk + soff;
                        wrow = Wh + (size_t)(j0 + srow) * H_ + kk + soff;
                        gs = (size_t)H_ * H_;
                    }
                    gl_lds16(arow,          &lds[nb][0][tid << 3]);
                    gl_lds16(wrow,          &lds[nb][1][tid << 3]);
                    gl_lds16(wrow + gs,     &lds[nb][2][tid << 3]);
                    gl_lds16(wrow + 2 * gs, &lds[nb][3][tid << 3]);
                };

                f32x4 accR[2][2] = {}, accZ[2][2] = {}, accI[2][2] = {}, accN[2][2] = {};

                stage(0, 0); stage(1, 1); stage(2, 2);

                for (int s = 0; s < nSup; ++s) {
                    int rem = nSup - 1 - s;
                    if (rem >= 2)      asm volatile("s_waitcnt vmcnt(8)" ::: "memory");
                    else if (rem == 1) asm volatile("s_waitcnt vmcnt(4)" ::: "memory");
                    else               asm volatile("s_waitcnt vmcnt(0)" ::: "memory");
                    __builtin_amdgcn_s_barrier();
                    if (s + 3 < nSup) stage(s + 3, (s + 3) & 3);
                    int cur = s & 3;

                    bf16x8 a0 = *(const bf16x8*)&lds[cur][0][aoff[0]];
                    bf16x8 a1 = *(const bf16x8*)&lds[cur][0][aoff[1]];
                    bf16x8 r0 = *(const bf16x8*)&lds[cur][1][boff[0]];
                    bf16x8 r1 = *(const bf16x8*)&lds[cur][1][boff[1]];
                    bf16x8 z0 = *(const bf16x8*)&lds[cur][2][boff[0]];
                    bf16x8 z1 = *(const bf16x8*)&lds[cur][2][boff[1]];
                    bf16x8 q0 = *(const bf16x8*)&lds[cur][3][boff[0]];
                    bf16x8 q1 = *(const bf16x8*)&lds[cur][3][boff[1]];

                    __builtin_amdgcn_s_setprio(1);
                    accR[0][0] = MFMA16(a0, r0, accR[0][0]);
                    accR[0][1] = MFMA16(a0, r1, accR[0][1]);
                    accR[1][0] = MFMA16(a1, r0, accR[1][0]);
                    accR[1][1] = MFMA16(a1, r1, accR[1][1]);
                    accZ[0][0] = MFMA16(a0, z0, accZ[0][0]);
                    accZ[0][1] = MFMA16(a0, z1, accZ[0][1]);
                    accZ[1][0] = MFMA16(a1, z0, accZ[1][0]);
                    accZ[1][1] = MFMA16(a1, z1, accZ[1][1]);
                    if (s < nX) {
                        accI[0][0] = MFMA16(a0, q0, accI[0][0]);
                        accI[0][1] = MFMA16(a0, q1, accI[0][1]);
                        accI[1][0] = MFMA16(a1, q0, accI[1][0]);
                        accI[1][1] = MFMA16(a1, q1, accI[1][1]);
                    } else {
                        accN[0][0] = MFMA16(a0, q0, accN[0][0]);
                        accN[0][1] = MFMA16(a0, q1, accN[0][1]);
                        accN[1][0] = MFMA16(a1, q0, accN[1][0]);
                        accN[1][1] = MFMA16(a1, q1, accN[1][1]);
                    }
                    __builtin_amdgcn_s_setprio(0);
                }

                // cross-group reduction: group1 -> LDS, group0 adds + epilogue
                float* red = (float*)&lds[0][0][0];   // 64 KiB (bufs 0-1)
                if (g == 1) {
#pragma unroll
                    for (int m = 0; m < 2; ++m)
#pragma unroll
                        for (int n = 0; n < 2; ++n) {
                            int mn = (m << 1) | n;
                            *(f32x4*)&red[((((quad << 2) + 0) << 2 | mn) * 64 + lane) << 2] = accR[m][n];
                            *(f32x4*)&red[((((quad << 2) + 1) << 2 | mn) * 64 + lane) << 2] = accZ[m][n];
                            *(f32x4*)&red[((((quad << 2) + 2) << 2 | mn) * 64 + lane) << 2] = accI[m][n];
                            *(f32x4*)&red[((((quad << 2) + 3) << 2 | mn) * 64 + lane) << 2] = accN[m][n];
                        }
                }
                __syncthreads();
                if (g == 0) {
#pragma unroll
                    for (int m = 0; m < 2; ++m)
#pragma unroll
                        for (int n = 0; n < 2; ++n) {
                            int mn = (m << 1) | n;
                            accR[m][n] += *(const f32x4*)&red[((((quad << 2) + 0) << 2 | mn) * 64 + lane) << 2];
                            accZ[m][n] += *(const f32x4*)&red[((((quad << 2) + 1) << 2 | mn) * 64 + lane) << 2];
                            accI[m][n] += *(const f32x4*)&red[((((quad << 2) + 2) << 2 | mn) * 64 + lane) << 2];
                            accN[m][n] += *(const f32x4*)&red[((((quad << 2) + 3) << 2 | mn) * 64 + lane) << 2];
                            int j = j0 + wc + 16 * n + fr;
                            float b_r = bi[j] + bh[j];
                            float b_z = bi[H_ + j] + bh[H_ + j];
                            float b_i = bi[2 * H_ + j];
                            float b_h = bh[2 * H_ + j];
#pragma unroll
                            for (int i = 0; i < 4; ++i) {
                                int brow = b0 + wr + 16 * m + kc * 4 + i;
                                float rv = 1.f / (1.f + __expf(-(accR[m][n][i] + b_r)));
                                float zv = 1.f / (1.f + __expf(-(accZ[m][n][i] + b_z)));
                                float nv = tanhf(accI[m][n][i] + b_i + rv * (accN[m][n][i] + b_h));
                                float hp = Hpf[(size_t)brow * H_ + j];
                                float hn = (1.f - zv) * nv + zv * hp;
                                hob[(size_t)brow * H_ + j] = f2b(hn);
                                hof[(size_t)brow * H_ + j] = hn;
                            }
                        }
                }
            } else {
                // ---------- linear head: out[:,t,:] = h2[t] @ WLt[t]^T + lb[t] ----------
                const u16* Al = p.h2a + (size_t)(t + 1) * BH_ + (size_t)b0 * H_;
                const u16* Wl = p.WLt + (size_t)t * (O_ * H_);

                auto stageL = [&](int s, int nb) {
                    int kk = s << 6;
                    gl_lds16(Al + (size_t)srow * H_ + kk + soff,        &lds[nb][0][tid << 3]);
                    gl_lds16(Wl + (size_t)(o0 + srow) * H_ + kk + soff, &lds[nb][1][tid << 3]);
                };

                f32x4 acc[2][2] = {};
                stageL(0, 0); stageL(1, 1); stageL(2, 2);
                for (int s = 0; s < nSup; ++s) {
                    int rem = nSup - 1 - s;
                    if (rem >= 2)      asm volatile("s_waitcnt vmcnt(4)" ::: "memory");
                    else if (rem == 1) asm volatile("s_waitcnt vmcnt(2)" ::: "memory");
                    else               asm volatile("s_waitcnt vmcnt(0)" ::: "memory");
                    __builtin_amdgcn_s_barrier();
                    if (s + 3 < nSup) stageL(s + 3, (s + 3) & 3);
                    int cur = s & 3;
                    bf16x8 a0 = *(const bf16x8*)&lds[cur][0][aoff[0]];
                    bf16x8 a1 = *(const bf16x8*)&lds[cur][0][aoff[1]];
                    bf16x8 w0 = *(const bf16x8*)&lds[cur][1][boff[0]];
                    bf16x8 w1 = *(const bf16x8*)&lds[cur][1][boff[1]];
                    __builtin_amdgcn_s_setprio(1);
                    acc[0][0] = MFMA16(a0, w0, acc[0][0]);
                    acc[0][1] = MFMA16(a0, w1, acc[0][1]);
                    acc[1][0] = MFMA16(a1, w0, acc[1][0]);
                    acc[1][1] = MFMA16(a1, w1, acc[1][1]);
                    __builtin_amdgcn_s_setprio(0);
                }

                float* red = (float*)&lds[0][0][0];
                if (g == 1) {
#pragma unroll
                    for (int m = 0; m < 2; ++m)
#pragma unroll
                        for (int n = 0; n < 2; ++n) {
                            int mn = (m << 1) | n;
                            *(f32x4*)&red[(((quad << 4) | mn) * 64 + lane) << 2] = acc[m][n];
                        }
                }
                __syncthreads();
                if (g == 0) {
#pragma unroll
                    for (int m = 0; m < 2; ++m)
#pragma unroll
                        for (int n = 0; n < 2; ++n) {
                            int mn = (m << 1) | n;
                            acc[m][n] += *(const f32x4*)&red[(((quad << 4) | mn) * 64 + lane) << 2];
                            int o = o0 + wc + 16 * n + fr;
                            float bb = p.lb[t * O_ + o];
#pragma unroll
                            for (int i = 0; i < 4; ++i) {
                                int brow = b0 + wr + 16 * m + kc * 4 + i;
                                p.out[((size_t)brow * S_ + t) * O_ + o] = acc[m][n][i] + bb;
                            }
                        }
                }
            }
        }
        grid.sync();
    }
}

// ---------------- final hidden-state outputs ----------------

__global__ void k_finals(const float* __restrict__ h0f, const float* __restrict__ h1f,
                         const float* __restrict__ h2f, float* __restrict__ out) {
    int i = blockIdx.x * blockDim.x + threadIdx.x;     // 3*BH_
    int c = i / BH_, r = i - c * BH_;
    // t=63 -> slot 63&1 = 1
    const float* s = (c == 0) ? (h0f + BH_) : (c == 1) ? (h1f + BH_) : (h2f + BH_);
    out[(size_t)B_ * S_ * O_ + (size_t)c * BH_ + r] = s[r];
}

// ---------------- launch ----------------

extern "C" void kernel_launch(void* const* d_in, const int* in_sizes, int n_in,
                              void* d_out, int out_size, void* d_ws, size_t ws_size,
                              hipStream_t stream) {
    (void)in_sizes; (void)n_in; (void)out_size; (void)ws_size;
    const float* x   = (const float*)d_in[0];
    const float* wi0 = (const float*)d_in[1];
    const float* wh0 = (const float*)d_in[2];
    const float* bi0 = (const float*)d_in[3];
    const float* bh0 = (const float*)d_in[4];
    const float* wi1 = (const float*)d_in[5];
    const float* wh1 = (const float*)d_in[6];
    const float* bi1 = (const float*)d_in[7];
    const float* bh1 = (const float*)d_in[8];
    const float* wi2 = (const float*)d_in[9];
    const float* wh2 = (const float*)d_in[10];
    const float* bi2 = (const float*)d_in[11];
    const float* bh2 = (const float*)d_in[12];
    const float* lw  = (const float*)d_in[13];
    const float* lb  = (const float*)d_in[14];

    char* base = (char*)d_ws;
    size_t off = 0;
    auto alloc = [&](size_t bytes) {
        char* p = base + off;
        off = (off + bytes + 255) & ~(size_t)255;
        return p;
    };
    u16* Xb  = (u16*)alloc((size_t)B_ * S_ * D_ * 2);
    u16* Wi0 = (u16*)alloc((size_t)G_ * D_ * 2);
    u16* Wh0 = (u16*)alloc((size_t)G_ * H_ * 2);
    u16* Wi1 = (u16*)alloc((size_t)G_ * H_ * 2);
    u16* Wh1 = (u16*)alloc((size_t)G_ * H_ * 2);
    u16* Wi2 = (u16*)alloc((size_t)G_ * H_ * 2);
    u16* Wh2 = (u16*)alloc((size_t)G_ * H_ * 2);
    u16* h0b = (u16*)alloc((size_t)2 * BH_ * 2);
    u16* h1b = (u16*)alloc((size_t)2 * BH_ * 2);
    u16* h2a = (u16*)alloc((size_t)(S_ + 1) * BH_ * 2);
    float* h0f = (float*)alloc((size_t)2 * BH_ * 4);
    float* h1f = (float*)alloc((size_t)2 * BH_ * 4);
    float* h2f = (float*)alloc((size_t)2 * BH_ * 4);
    u16* WLt = (u16*)alloc((size_t)S_ * O_ * H_ * 2);

    k_conv<<<1024, 256, 0, stream>>>(x,   Xb,  (B_ * S_ * D_) / 4);
    k_conv<<<1024, 256, 0, stream>>>(wi0, Wi0, (G_ * D_) / 4);
    k_conv<<<1024, 256, 0, stream>>>(wh0, Wh0, (G_ * H_) / 4);
    k_conv<<<1024, 256, 0, stream>>>(wi1, Wi1, (G_ * H_) / 4);
    k_conv<<<1024, 256, 0, stream>>>(wh1, Wh1, (G_ * H_) / 4);
    k_conv<<<1024, 256, 0, stream>>>(wi2, Wi2, (G_ * H_) / 4);
    k_conv<<<1024, 256, 0, stream>>>(wh2, Wh2, (G_ * H_) / 4);
    k_twl<<<S_ * 512, 256, 0, stream>>>(lw, WLt);
    hipMemsetAsync(h0b, 0, (size_t)2 * BH_ * 2, stream);
    hipMemsetAsync(h1b, 0, (size_t)2 * BH_ * 2, stream);
    hipMemsetAsync(h2a, 0, (size_t)BH_ * 2, stream);          // slot 0 = t=-1
    hipMemsetAsync(h0f, 0, (size_t)2 * BH_ * 4, stream);
    hipMemsetAsync(h1f, 0, (size_t)2 * BH_ * 4, stream);
    hipMemsetAsync(h2f, 0, (size_t)2 * BH_ * 4, stream);

    GruArgs ga;
    ga.Xb = Xb;
    ga.Wi0 = Wi0; ga.Wh0 = Wh0; ga.Wi1 = Wi1; ga.Wh1 = Wh1; ga.Wi2 = Wi2; ga.Wh2 = Wh2;
    ga.bi0 = bi0; ga.bh0 = bh0; ga.bi1 = bi1; ga.bh1 = bh1; ga.bi2 = bi2; ga.bh2 = bh2;
    ga.h0b = h0b; ga.h1b = h1b; ga.h2a = h2a;
    ga.h0f = h0f; ga.h1f = h1f; ga.h2f = h2f;
    ga.WLt = WLt; ga.lb = lb; ga.out = (float*)d_out;

    void* args[] = {&ga};
    hipLaunchCooperativeKernel((void*)k_gru, dim3(224), dim3(512), args, 0, stream);

    k_finals<<<(3 * BH_) / 256, 256, 0, stream>>>(h0f, h1f, h2f, (float*)d_out);
}

// Round 5
// 2919.381 us; speedup vs baseline: 1.1506x; 1.1437x over previous
//
#include <hip/hip_runtime.h>
#include <hip/hip_bf16.h>
#include <stdint.h>

#define B_ 256
#define S_ 64
#define D_ 256
#define H_ 1024
#define O_ 512
#define G_ 3072          // 3*H
#define BH_ (B_ * H_)    // 262144

typedef unsigned short u16;
typedef __attribute__((ext_vector_type(8))) short bf16x8;
typedef __attribute__((ext_vector_type(4))) float f32x4;

#define MFMA16(a, b, c) __builtin_amdgcn_mfma_f32_16x16x32_bf16((a), (b), (c), 0, 0, 0)

__device__ __forceinline__ u16 f2b(float f) {
    union { float f; uint32_t u; } v; v.f = f;
    uint32_t u = v.u;
    return (u16)((u + 0x7fffu + ((u >> 16) & 1u)) >> 16);   // RNE
}

__device__ __forceinline__ void gl_lds16(const u16* g, u16* l) {
    __builtin_amdgcn_global_load_lds(
        (const __attribute__((address_space(1))) unsigned int*)g,
        (__attribute__((address_space(3))) unsigned int*)l, 16, 0, 0);
}
__device__ __forceinline__ unsigned long long sysld64(const u16* p) {
    return __hip_atomic_load((const unsigned long long*)p, __ATOMIC_RELAXED, __HIP_MEMORY_SCOPE_SYSTEM);
}
__device__ __forceinline__ void sysst64(u16* p, unsigned long long v) {
    __hip_atomic_store((unsigned long long*)p, v, __ATOMIC_RELAXED, __HIP_MEMORY_SCOPE_SYSTEM);
}
__device__ __forceinline__ void waitflag(int* f, int n) {
    while (__hip_atomic_load(f, __ATOMIC_RELAXED, __HIP_MEMORY_SCOPE_SYSTEM) < n)
        __builtin_amdgcn_s_sleep(8);
    asm volatile("" ::: "memory");
}
__device__ __forceinline__ void postflag(int* f) {
    __hip_atomic_fetch_add(f, 1, __ATOMIC_RELAXED, __HIP_MEMORY_SCOPE_SYSTEM);
}

// ---------------- prep kernels ----------------

__global__ void k_conv(const float* __restrict__ s, u16* __restrict__ d, int n4) {
    int i = blockIdx.x * blockDim.x + threadIdx.x;
    int st = gridDim.x * blockDim.x;
    for (; i < n4; i += st) {
        float4 v = ((const float4*)s)[i];
        ushort4 o;
        o.x = f2b(v.x); o.y = f2b(v.y); o.z = f2b(v.z); o.w = f2b(v.w);
        ((ushort4*)d)[i] = o;
    }
}

// lin_w [S][H][O] f32 -> [S][O][H] bf16
__global__ __launch_bounds__(256) void k_twl(const float* __restrict__ w, u16* __restrict__ o) {
    __shared__ float tile[32][33];
    int bid = blockIdx.x;
    int t = bid >> 9;
    int rem = bid & 511;
    int j0 = (rem >> 4) << 5;
    int o0 = (rem & 15) << 5;
    int tx = threadIdx.x & 31, ty = threadIdx.x >> 5;
    const float* base = w + (size_t)t * (H_ * O_);
#pragma unroll
    for (int i = 0; i < 4; ++i) {
        int r = ty + (i << 3);
        tile[r][tx] = base[(size_t)(j0 + r) * O_ + o0 + tx];
    }
    __syncthreads();
    u16* ob = o + (size_t)t * (O_ * H_);
#pragma unroll
    for (int i = 0; i < 4; ++i) {
        int r = ty + (i << 3);
        ob[(size_t)(o0 + r) * H_ + j0 + tx] = f2b(tile[tx][r]);
    }
}

// ---------------- persistent dataflow GRU + linear head ----------------

struct GruArgs {
    const u16* Xb;
    const u16 *Wi0, *Wh0, *Wi1, *Wh1, *Wi2, *Wh2;
    const float *bi0, *bh0, *bi1, *bh1, *bi2, *bh2;
    u16 *h0, *h1, *h2a;      // h0,h1: 8-slot rings; h2a: 65 slots (slot t+1 = time t)
    const u16* WLt;          // [S][O][H] bf16
    const float* lb;         // [S][O]
    float* out;              // [B][S][O] then h0,h1,h2 finals
    int* ready;              // [8 groups][3 cells][64 t]
    int* consumed;           // [8 groups][2 cells][64 t]
};

__global__ __launch_bounds__(512, 1) void k_gru(GruArgs p) {
    __shared__ u16 Wb[2][3][128 * 64];   // 96 KiB weight double-buffer (3 gates)
    __shared__ u16 Ab[2][32 * 64];       // 8 KiB A double-buffer
    __shared__ float carry[32 * 132];    // 16.9 KiB fp32 recurrent state (padded)

    const int w = blockIdx.x;
    const int g = w & 7;                 // logical group (b-rows), targets XCD via %8
    const int slot = w >> 3;             // 0..31
    const int role = slot >> 3;          // 0,1,2 = GRU cells; 3 = linear head
    const int sub = slot & 7;
    const int b0 = g * 32;

    const int tid = threadIdx.x;
    const int wid = tid >> 6, lane = tid & 63;
    const int fr = lane & 15, kc = lane >> 4;

    // staging constants (A-tile: 32 rows x 64 k, 8B per thread)
    const int arow = tid >> 4;
    const int acol = (tid & 15) << 2;                                        // u16 offset
    const int adst = arow * 64 + ((((tid & 15) >> 1) ^ (arow & 7)) << 3) + ((tid & 1) << 2);

    int sw0 = ((kc ^ (fr & 7)) << 3);
    int sw1 = (((4 + kc) ^ (fr & 7)) << 3);

    int* ready = p.ready + g * 3 * 64;
    int* consumed = p.consumed + g * 2 * 64;

    for (int i = tid; i < 32 * 132; i += 512) carry[i] = 0.f;
    __syncthreads();

    if (role < 3) {
        // ================= GRU cell =================
        const u16 *Wi, *Wh; const float *bi, *bh; int K0;
        if (role == 0)      { Wi = p.Wi0; Wh = p.Wh0; bi = p.bi0; bh = p.bh0; K0 = D_; }
        else if (role == 1) { Wi = p.Wi1; Wh = p.Wh1; bi = p.bi1; bh = p.bh1; K0 = H_; }
        else                { Wi = p.Wi2; Wh = p.Wh2; bi = p.bi2; bh = p.bh2; K0 = H_; }
        const int nXc = K0 >> 6;
        const int nC = nXc + 16;
        const int j0 = sub * 128;
        const int jme = j0 + (wid << 4) + fr;
        const float b_r = bi[jme] + bh[jme];
        const float b_z = bi[H_ + jme] + bh[H_ + jme];
        const float b_i = bi[2 * H_ + jme];
        const float b_h = bh[2 * H_ + jme];

        const u16 *A0 = nullptr, *Ah = nullptr; int ld0 = H_;
        u16* hout = nullptr;

        auto LA = [&](int c) -> unsigned long long {
            const u16* s = (c < nXc) ? (A0 + (size_t)arow * ld0 + (c << 6) + acol)
                                     : (Ah + (size_t)arow * H_ + ((c - nXc) << 6) + acol);
            return sysld64(s);
        };
        auto SW = [&](int c, int nb) {
            if (c < nXc) {
                int ko = c << 6;
#pragma unroll
                for (int hh = 0; hh < 2; ++hh) {
                    int ci = (hh << 9) + tid, jr = ci >> 3, c8 = ci & 7;
                    size_t ro = (size_t)(j0 + jr) * K0 + ko + ((c8 ^ (jr & 7)) << 3);
                    gl_lds16(Wi + ro,                     &Wb[nb][0][ci << 3]);
                    gl_lds16(Wi + (size_t)H_ * K0 + ro,   &Wb[nb][1][ci << 3]);
                    gl_lds16(Wi + (size_t)2 * H_ * K0 + ro, &Wb[nb][2][ci << 3]);
                }
            } else {
                int ko = (c - nXc) << 6;
#pragma unroll
                for (int hh = 0; hh < 2; ++hh) {
                    int ci = (hh << 9) + tid, jr = ci >> 3, c8 = ci & 7;
                    size_t ro = (size_t)(j0 + jr) * H_ + ko + ((c8 ^ (jr & 7)) << 3);
                    gl_lds16(Wh + ro,                     &Wb[nb][0][ci << 3]);
                    gl_lds16(Wh + (size_t)H_ * H_ + ro,   &Wb[nb][1][ci << 3]);
                    gl_lds16(Wh + (size_t)2 * H_ * H_ + ro, &Wb[nb][2][ci << 3]);
                }
            }
        };

        for (int t = 0; t < S_; ++t) {
            // dependency waits
            if (role == 0) {
                if (t) waitflag(&ready[0 * 64 + t - 1], 8);
                A0 = p.Xb + (size_t)b0 * (S_ * D_) + t * D_; ld0 = S_ * D_;
                Ah = p.h0 + (size_t)((t + 7) & 7) * BH_ + (size_t)b0 * H_;
                hout = p.h0 + (size_t)(t & 7) * BH_;
            } else if (role == 1) {
                waitflag(&ready[0 * 64 + t], 8);
                if (t) waitflag(&ready[1 * 64 + t - 1], 8);
                A0 = p.h0 + (size_t)(t & 7) * BH_ + (size_t)b0 * H_; ld0 = H_;
                Ah = p.h1 + (size_t)((t + 7) & 7) * BH_ + (size_t)b0 * H_;
                hout = p.h1 + (size_t)(t & 7) * BH_;
            } else {
                waitflag(&ready[1 * 64 + t], 8);
                if (t) waitflag(&ready[2 * 64 + t - 1], 8);
                A0 = p.h1 + (size_t)(t & 7) * BH_ + (size_t)b0 * H_; ld0 = H_;
                Ah = p.h2a + (size_t)t * BH_ + (size_t)b0 * H_;
                hout = p.h2a + (size_t)(t + 1) * BH_;
            }

            f32x4 accR[2] = {}, accZ[2] = {}, accI[2] = {}, accN[2] = {};

            // prologue
            unsigned long long la0 = LA(0), la1 = LA(1);
            *(unsigned long long*)&Ab[0][adst] = la0;
            SW(0, 0);
            la0 = LA(2);

            auto BODY = [&](int s, unsigned long long& laReg) {
                if (s + 2 < nC) asm volatile("s_waitcnt vmcnt(1)" ::: "memory");
                else            asm volatile("s_waitcnt vmcnt(0)" ::: "memory");
                asm volatile("s_waitcnt lgkmcnt(0)" ::: "memory");
                __builtin_amdgcn_s_barrier();
                __builtin_amdgcn_sched_barrier(0);
                if (s + 1 < nC) {
                    *(unsigned long long*)&Ab[(s + 1) & 1][adst] = laReg;
                    SW(s + 1, (s + 1) & 1);
                }
                if (s + 3 < nC) laReg = LA(s + 3);
                const int cur = s & 1;
                const int bo = ((wid << 4) + fr) * 64;
                bf16x8 a00 = *(const bf16x8*)&Ab[cur][fr * 64 + sw0];
                bf16x8 a01 = *(const bf16x8*)&Ab[cur][fr * 64 + sw1];
                bf16x8 a10 = *(const bf16x8*)&Ab[cur][(16 + fr) * 64 + sw0];
                bf16x8 a11 = *(const bf16x8*)&Ab[cur][(16 + fr) * 64 + sw1];
                bf16x8 r0 = *(const bf16x8*)&Wb[cur][0][bo + sw0];
                bf16x8 r1 = *(const bf16x8*)&Wb[cur][0][bo + sw1];
                bf16x8 z0 = *(const bf16x8*)&Wb[cur][1][bo + sw0];
                bf16x8 z1 = *(const bf16x8*)&Wb[cur][1][bo + sw1];
                bf16x8 q0 = *(const bf16x8*)&Wb[cur][2][bo + sw0];
                bf16x8 q1 = *(const bf16x8*)&Wb[cur][2][bo + sw1];
                __builtin_amdgcn_s_setprio(1);
                accR[0] = MFMA16(a00, r0, accR[0]); accR[0] = MFMA16(a01, r1, accR[0]);
                accR[1] = MFMA16(a10, r0, accR[1]); accR[1] = MFMA16(a11, r1, accR[1]);
                accZ[0] = MFMA16(a00, z0, accZ[0]); accZ[0] = MFMA16(a01, z1, accZ[0]);
                accZ[1] = MFMA16(a10, z0, accZ[1]); accZ[1] = MFMA16(a11, z1, accZ[1]);
                if (s < nXc) {
                    accI[0] = MFMA16(a00, q0, accI[0]); accI[0] = MFMA16(a01, q1, accI[0]);
                    accI[1] = MFMA16(a10, q0, accI[1]); accI[1] = MFMA16(a11, q1, accI[1]);
                } else {
                    accN[0] = MFMA16(a00, q0, accN[0]); accN[0] = MFMA16(a01, q1, accN[0]);
                    accN[1] = MFMA16(a10, q0, accN[1]); accN[1] = MFMA16(a11, q1, accN[1]);
                }
                __builtin_amdgcn_s_setprio(0);
            };
            for (int s = 0; s < nC; s += 2) { BODY(s, la1); BODY(s + 1, la0); }

            // backpressure before overwriting the 8-slot ring
            if (role <= 1 && t >= 8) waitflag(&consumed[role * 64 + (t - 8)], 16);

            // gates + state update; bf16 repack in LDS, fp32 carry stays in LDS
            u16* hrep = &Wb[0][0][0];
#pragma unroll
            for (int m = 0; m < 2; ++m)
#pragma unroll
                for (int i = 0; i < 4; ++i) {
                    int row = m * 16 + kc * 4 + i;
                    float rv = 1.f / (1.f + __expf(-(accR[m][i] + b_r)));
                    float zv = 1.f / (1.f + __expf(-(accZ[m][i] + b_z)));
                    float nv = tanhf(accI[m][i] + b_i + rv * (accN[m][i] + b_h));
                    float hp = carry[row * 132 + (wid << 4) + fr];
                    float hn = (1.f - zv) * nv + zv * hp;
                    carry[row * 132 + (wid << 4) + fr] = hn;
                    hrep[row * 128 + (wid << 4) + fr] = f2b(hn);
                }
            __syncthreads();
            {
                int rr = tid >> 4, jo = (tid & 15) << 3;
                unsigned long long v0 = *(const unsigned long long*)&hrep[rr * 128 + jo];
                unsigned long long v1 = *(const unsigned long long*)&hrep[rr * 128 + jo + 4];
                u16* dst = hout + (size_t)(b0 + rr) * H_ + j0 + jo;
                sysst64(dst, v0);
                sysst64(dst + 4, v1);
            }
            if (t == S_ - 1) {
                int rr = tid >> 4, jo = (tid & 15) << 3;
                float* od = p.out + (size_t)B_ * S_ * O_ + (size_t)role * BH_ +
                            (size_t)(b0 + rr) * H_ + j0 + jo;
                *(float4*)od       = *(const float4*)&carry[rr * 132 + jo];
                *(float4*)(od + 4) = *(const float4*)&carry[rr * 132 + jo + 4];
            }
            asm volatile("s_waitcnt vmcnt(0)" ::: "memory");
            __syncthreads();
            if (tid == 0) {
                postflag(&ready[role * 64 + t]);
                if (role >= 1) postflag(&consumed[(role - 1) * 64 + t]);
                if (role <= 1 && t) postflag(&consumed[role * 64 + (t - 1)]);
            }
            __syncthreads();
        }
    } else {
        // ================= linear head =================
        const int o0 = sub << 6;
        const int nC = 16;
        const int mg = wid >> 2, og = wid & 3;
        const u16 *A0 = nullptr, *Wl = nullptr;

        auto LAl = [&](int c) -> unsigned long long {
            return sysld64(A0 + (size_t)arow * H_ + (c << 6) + acol);
        };
        auto SWl = [&](int c, int nb) {
            int orow = tid >> 3, c8 = tid & 7;
            gl_lds16(Wl + (size_t)(o0 + orow) * H_ + (c << 6) + ((c8 ^ (orow & 7)) << 3),
                     &Wb[nb][0][tid << 3]);
        };

        for (int t = 0; t < S_; ++t) {
            waitflag(&ready[2 * 64 + t], 8);
            A0 = p.h2a + (size_t)(t + 1) * BH_ + (size_t)b0 * H_;
            Wl = p.WLt + (size_t)t * (O_ * H_);

            f32x4 acc = {0.f, 0.f, 0.f, 0.f};
            unsigned long long la0 = LAl(0), la1 = LAl(1);
            *(unsigned long long*)&Ab[0][adst] = la0;
            SWl(0, 0);
            la0 = LAl(2);

            auto BODYL = [&](int s, unsigned long long& laReg) {
                if (s + 2 < nC) asm volatile("s_waitcnt vmcnt(1)" ::: "memory");
                else            asm volatile("s_waitcnt vmcnt(0)" ::: "memory");
                asm volatile("s_waitcnt lgkmcnt(0)" ::: "memory");
                __builtin_amdgcn_s_barrier();
                __builtin_amdgcn_sched_barrier(0);
                if (s + 1 < nC) {
                    *(unsigned long long*)&Ab[(s + 1) & 1][adst] = laReg;
                    SWl(s + 1, (s + 1) & 1);
                }
                if (s + 3 < nC) laReg = LAl(s + 3);
                const int cur = s & 1;
                bf16x8 a0 = *(const bf16x8*)&Ab[cur][(mg * 16 + fr) * 64 + sw0];
                bf16x8 a1 = *(const bf16x8*)&Ab[cur][(mg * 16 + fr) * 64 + sw1];
                bf16x8 w0 = *(const bf16x8*)&Wb[cur][0][(og * 16 + fr) * 64 + sw0];
                bf16x8 w1 = *(const bf16x8*)&Wb[cur][0][(og * 16 + fr) * 64 + sw1];
                __builtin_amdgcn_s_setprio(1);
                acc = MFMA16(a0, w0, acc);
                acc = MFMA16(a1, w1, acc);
                __builtin_amdgcn_s_setprio(0);
            };
            for (int s = 0; s < nC; s += 2) { BODYL(s, la1); BODYL(s + 1, la0); }

            float bb = p.lb[t * O_ + o0 + og * 16 + fr];
#pragma unroll
            for (int i = 0; i < 4; ++i) {
                int row = mg * 16 + kc * 4 + i;
                p.out[((size_t)(b0 + row) * S_ + t) * O_ + o0 + og * 16 + fr] = acc[i] + bb;
            }
        }
    }
}

// ---------------- launch ----------------

extern "C" void kernel_launch(void* const* d_in, const int* in_sizes, int n_in,
                              void* d_out, int out_size, void* d_ws, size_t ws_size,
                              hipStream_t stream) {
    (void)in_sizes; (void)n_in; (void)out_size; (void)ws_size;
    const float* x   = (const float*)d_in[0];
    const float* wi0 = (const float*)d_in[1];
    const float* wh0 = (const float*)d_in[2];
    const float* bi0 = (const float*)d_in[3];
    const float* bh0 = (const float*)d_in[4];
    const float* wi1 = (const float*)d_in[5];
    const float* wh1 = (const float*)d_in[6];
    const float* bi1 = (const float*)d_in[7];
    const float* bh1 = (const float*)d_in[8];
    const float* wi2 = (const float*)d_in[9];
    const float* wh2 = (const float*)d_in[10];
    const float* bi2 = (const float*)d_in[11];
    const float* bh2 = (const float*)d_in[12];
    const float* lw  = (const float*)d_in[13];
    const float* lb  = (const float*)d_in[14];

    char* base = (char*)d_ws;
    size_t off = 0;
    auto alloc = [&](size_t bytes) {
        char* p = base + off;
        off = (off + bytes + 255) & ~(size_t)255;
        return p;
    };
    u16* Xb  = (u16*)alloc((size_t)B_ * S_ * D_ * 2);
    u16* Wi0 = (u16*)alloc((size_t)G_ * D_ * 2);
    u16* Wh0 = (u16*)alloc((size_t)G_ * H_ * 2);
    u16* Wi1 = (u16*)alloc((size_t)G_ * H_ * 2);
    u16* Wh1 = (u16*)alloc((size_t)G_ * H_ * 2);
    u16* Wi2 = (u16*)alloc((size_t)G_ * H_ * 2);
    u16* Wh2 = (u16*)alloc((size_t)G_ * H_ * 2);
    u16* h0  = (u16*)alloc((size_t)8 * BH_ * 2);
    u16* h1  = (u16*)alloc((size_t)8 * BH_ * 2);
    u16* h2a = (u16*)alloc((size_t)(S_ + 1) * BH_ * 2);
    u16* WLt = (u16*)alloc((size_t)S_ * O_ * H_ * 2);
    int* flags = (int*)alloc((size_t)(8 * 3 * 64 + 8 * 2 * 64) * 4);
    int* ready = flags;
    int* consumed = flags + 8 * 3 * 64;

    k_conv<<<1024, 256, 0, stream>>>(x,   Xb,  (B_ * S_ * D_) / 4);
    k_conv<<<1024, 256, 0, stream>>>(wi0, Wi0, (G_ * D_) / 4);
    k_conv<<<1024, 256, 0, stream>>>(wh0, Wh0, (G_ * H_) / 4);
    k_conv<<<1024, 256, 0, stream>>>(wi1, Wi1, (G_ * H_) / 4);
    k_conv<<<1024, 256, 0, stream>>>(wh1, Wh1, (G_ * H_) / 4);
    k_conv<<<1024, 256, 0, stream>>>(wi2, Wi2, (G_ * H_) / 4);
    k_conv<<<1024, 256, 0, stream>>>(wh2, Wh2, (G_ * H_) / 4);
    k_twl<<<S_ * 512, 256, 0, stream>>>(lw, WLt);
    hipMemsetAsync(h0 + (size_t)7 * BH_, 0, (size_t)BH_ * 2, stream);   // h0[-1] = 0
    hipMemsetAsync(h1 + (size_t)7 * BH_, 0, (size_t)BH_ * 2, stream);   // h1[-1] = 0
    hipMemsetAsync(h2a, 0, (size_t)BH_ * 2, stream);                    // h2[-1] = 0
    hipMemsetAsync(flags, 0, (size_t)(8 * 3 * 64 + 8 * 2 * 64) * 4, stream);

    GruArgs ga;
    ga.Xb = Xb;
    ga.Wi0 = Wi0; ga.Wh0 = Wh0; ga.Wi1 = Wi1; ga.Wh1 = Wh1; ga.Wi2 = Wi2; ga.Wh2 = Wh2;
    ga.bi0 = bi0; ga.bh0 = bh0; ga.bi1 = bi1; ga.bh1 = bh1; ga.bi2 = bi2; ga.bh2 = bh2;
    ga.h0 = h0; ga.h1 = h1; ga.h2a = h2a;
    ga.WLt = WLt; ga.lb = lb; ga.out = (float*)d_out;
    ga.ready = ready; ga.consumed = consumed;

    void* args[] = {&ga};
    hipLaunchCooperativeKernel((void*)k_gru, dim3(256), dim3(512), args, 0, stream);
}

// Round 6
// 2615.025 us; speedup vs baseline: 1.2845x; 1.1164x over previous
//
#include <hip/hip_runtime.h>
#include <hip/hip_bf16.h>
#include <stdint.h>

#define B_ 256
#define S_ 64
#define D_ 256
#define H_ 1024
#define O_ 512
#define G_ 3072          // 3*H
#define BH_ (B_ * H_)    // 262144
#define RING_ 32

typedef unsigned short u16;
typedef __attribute__((ext_vector_type(8))) short bf16x8;
typedef __attribute__((ext_vector_type(4))) float f32x4;

#define MFMA16(a, b, c) __builtin_amdgcn_mfma_f32_16x16x32_bf16((a), (b), (c), 0, 0, 0)

__device__ __forceinline__ u16 f2b(float f) {
    union { float f; uint32_t u; } v; v.f = f;
    uint32_t u = v.u;
    return (u16)((u + 0x7fffu + ((u >> 16) & 1u)) >> 16);   // RNE
}

__device__ __forceinline__ void gl_lds16(const u16* g, u16* l) {
    __builtin_amdgcn_global_load_lds(
        (const __attribute__((address_space(1))) unsigned int*)g,
        (__attribute__((address_space(3))) unsigned int*)l, 16, 0, 0);
}
__device__ __forceinline__ unsigned long long sysld64(const u16* p) {
    return __hip_atomic_load((const unsigned long long*)p, __ATOMIC_RELAXED, __HIP_MEMORY_SCOPE_SYSTEM);
}
__device__ __forceinline__ void sysst64(u16* p, unsigned long long v) {
    __hip_atomic_store((unsigned long long*)p, v, __ATOMIC_RELAXED, __HIP_MEMORY_SCOPE_SYSTEM);
}
__device__ __forceinline__ void waitflag(int* f, int n) {
    while (__hip_atomic_load(f, __ATOMIC_RELAXED, __HIP_MEMORY_SCOPE_SYSTEM) < n)
        __builtin_amdgcn_s_sleep(8);
    asm volatile("" ::: "memory");
}
__device__ __forceinline__ void postflag(int* f) {
    __hip_atomic_fetch_add(f, 1, __ATOMIC_RELAXED, __HIP_MEMORY_SCOPE_SYSTEM);
}

// ---------------- prep kernels ----------------

__global__ void k_conv(const float* __restrict__ s, u16* __restrict__ d, int n4) {
    int i = blockIdx.x * blockDim.x + threadIdx.x;
    int st = gridDim.x * blockDim.x;
    for (; i < n4; i += st) {
        float4 v = ((const float4*)s)[i];
        ushort4 o;
        o.x = f2b(v.x); o.y = f2b(v.y); o.z = f2b(v.z); o.w = f2b(v.w);
        ((ushort4*)d)[i] = o;
    }
}

// lin_w [S][H][O] f32 -> [S][O][H] bf16
__global__ __launch_bounds__(256) void k_twl(const float* __restrict__ w, u16* __restrict__ o) {
    __shared__ float tile[32][33];
    int bid = blockIdx.x;
    int t = bid >> 9;
    int rem = bid & 511;
    int j0 = (rem >> 4) << 5;
    int o0 = (rem & 15) << 5;
    int tx = threadIdx.x & 31, ty = threadIdx.x >> 5;
    const float* base = w + (size_t)t * (H_ * O_);
#pragma unroll
    for (int i = 0; i < 4; ++i) {
        int r = ty + (i << 3);
        tile[r][tx] = base[(size_t)(j0 + r) * O_ + o0 + tx];
    }
    __syncthreads();
    u16* ob = o + (size_t)t * (O_ * H_);
#pragma unroll
    for (int i = 0; i < 4; ++i) {
        int r = ty + (i << 3);
        ob[(size_t)(o0 + r) * H_ + j0 + tx] = f2b(tile[tx][r]);
    }
}

// ---------------- persistent dataflow GRU + linear head ----------------
// Partition: XCD owns j-slice of EVERY cell's weights (L2-resident, ~4.1 MB);
// the 8 WGs per (cell, XCD) split the batch (b32 each).

struct GruArgs {
    const u16* Xb;
    const u16 *Wi0, *Wh0, *Wi1, *Wh1, *Wi2, *Wh2;
    const float *bi0, *bh0, *bi1, *bh1, *bi2, *bh2;
    u16 *h0, *h1, *h2a;      // h0,h1: 32-slot rings; h2a: 65 slots (slot t+1 = time t)
    const u16* WLt;          // [S][O][H] bf16
    const float* lb;         // [S][O]
    float* out;              // [B][S][O] then h0,h1,h2 finals
    int* ready;              // [3 cells][64 t]   -> counts to 64
    int* consumed;           // [2 cells][64 t]   -> counts to 128
};

__global__ __launch_bounds__(512, 1) void k_gru(GruArgs p) {
    __shared__ u16 Wb[2][3][128 * 64];   // 96 KiB weight double-buffer (3 gates)
    __shared__ u16 Ab[2][32 * 64];       // 8 KiB A double-buffer
    __shared__ float carry[32 * 132];    // 16.9 KiB fp32 recurrent state (padded)

    const int w = blockIdx.x;
    const int xcd = w & 7;               // weight j-slice owner (targets XCD via %8)
    const int slot = w >> 3;             // 0..31
    const int role = slot >> 3;          // 0,1,2 = GRU cells; 3 = linear head
    const int sub = slot & 7;            // batch tile
    const int b0 = sub * 32;

    const int tid = threadIdx.x;
    const int wid = tid >> 6, lane = tid & 63;
    const int fr = lane & 15, kc = lane >> 4;

    // staging constants (A-tile: 32 rows x 64 k, 8B per thread)
    const int arow = tid >> 4;
    const int acol = (tid & 15) << 2;                                        // u16 offset
    const int adst = arow * 64 + ((((tid & 15) >> 1) ^ (arow & 7)) << 3) + ((tid & 1) << 2);

    int sw0 = ((kc ^ (fr & 7)) << 3);
    int sw1 = (((4 + kc) ^ (fr & 7)) << 3);

    int* ready = p.ready;
    int* consumed = p.consumed;

    for (int i = tid; i < 32 * 132; i += 512) carry[i] = 0.f;
    __syncthreads();

    if (role < 3) {
        // ================= GRU cell =================
        const u16 *Wi, *Wh; const float *bi, *bh; int K0;
        if (role == 0)      { Wi = p.Wi0; Wh = p.Wh0; bi = p.bi0; bh = p.bh0; K0 = D_; }
        else if (role == 1) { Wi = p.Wi1; Wh = p.Wh1; bi = p.bi1; bh = p.bh1; K0 = H_; }
        else                { Wi = p.Wi2; Wh = p.Wh2; bi = p.bi2; bh = p.bh2; K0 = H_; }
        const int nXc = K0 >> 6;
        const int nC = nXc + 16;
        const int j0 = xcd * 128;        // weight slice fixed per XCD
        const int jme = j0 + (wid << 4) + fr;
        const float b_r = bi[jme] + bh[jme];
        const float b_z = bi[H_ + jme] + bh[H_ + jme];
        const float b_i = bi[2 * H_ + jme];
        const float b_h = bh[2 * H_ + jme];

        const u16 *A0 = nullptr, *Ah = nullptr; int ld0 = H_;
        u16* hout = nullptr;

        auto LA = [&](int c) -> unsigned long long {
            const u16* s = (c < nXc) ? (A0 + (size_t)arow * ld0 + (c << 6) + acol)
                                     : (Ah + (size_t)arow * H_ + ((c - nXc) << 6) + acol);
            return sysld64(s);
        };
        auto SW = [&](int c, int nb) {
            if (c < nXc) {
                int ko = c << 6;
#pragma unroll
                for (int hh = 0; hh < 2; ++hh) {
                    int ci = (hh << 9) + tid, jr = ci >> 3, c8 = ci & 7;
                    size_t ro = (size_t)(j0 + jr) * K0 + ko + ((c8 ^ (jr & 7)) << 3);
                    gl_lds16(Wi + ro,                       &Wb[nb][0][ci << 3]);
                    gl_lds16(Wi + (size_t)H_ * K0 + ro,     &Wb[nb][1][ci << 3]);
                    gl_lds16(Wi + (size_t)2 * H_ * K0 + ro, &Wb[nb][2][ci << 3]);
                }
            } else {
                int ko = (c - nXc) << 6;
#pragma unroll
                for (int hh = 0; hh < 2; ++hh) {
                    int ci = (hh << 9) + tid, jr = ci >> 3, c8 = ci & 7;
                    size_t ro = (size_t)(j0 + jr) * H_ + ko + ((c8 ^ (jr & 7)) << 3);
                    gl_lds16(Wh + ro,                       &Wb[nb][0][ci << 3]);
                    gl_lds16(Wh + (size_t)H_ * H_ + ro,     &Wb[nb][1][ci << 3]);
                    gl_lds16(Wh + (size_t)2 * H_ * H_ + ro, &Wb[nb][2][ci << 3]);
                }
            }
        };

        for (int t = 0; t < S_; ++t) {
            // dependency waits (global: all 64 WGs of the producer cell)
            if (role == 0) {
                if (t) waitflag(&ready[0 * 64 + t - 1], 64);
                A0 = p.Xb + (size_t)b0 * (S_ * D_) + t * D_; ld0 = S_ * D_;
                Ah = p.h0 + (size_t)((t + RING_ - 1) & (RING_ - 1)) * BH_ + (size_t)b0 * H_;
                hout = p.h0 + (size_t)(t & (RING_ - 1)) * BH_;
            } else if (role == 1) {
                waitflag(&ready[0 * 64 + t], 64);
                if (t) waitflag(&ready[1 * 64 + t - 1], 64);
                A0 = p.h0 + (size_t)(t & (RING_ - 1)) * BH_ + (size_t)b0 * H_; ld0 = H_;
                Ah = p.h1 + (size_t)((t + RING_ - 1) & (RING_ - 1)) * BH_ + (size_t)b0 * H_;
                hout = p.h1 + (size_t)(t & (RING_ - 1)) * BH_;
            } else {
                waitflag(&ready[1 * 64 + t], 64);
                if (t) waitflag(&ready[2 * 64 + t - 1], 64);
                A0 = p.h1 + (size_t)(t & (RING_ - 1)) * BH_ + (size_t)b0 * H_; ld0 = H_;
                Ah = p.h2a + (size_t)t * BH_ + (size_t)b0 * H_;
                hout = p.h2a + (size_t)(t + 1) * BH_;
            }

            f32x4 accR[2] = {}, accZ[2] = {}, accI[2] = {}, accN[2] = {};

            // prologue
            unsigned long long la0 = LA(0), la1 = LA(1);
            *(unsigned long long*)&Ab[0][adst] = la0;
            SW(0, 0);
            la0 = LA(2);

            auto BODY = [&](int s, unsigned long long& laReg) {
                if (s + 2 < nC) asm volatile("s_waitcnt vmcnt(1)" ::: "memory");
                else            asm volatile("s_waitcnt vmcnt(0)" ::: "memory");
                asm volatile("s_waitcnt lgkmcnt(0)" ::: "memory");
                __builtin_amdgcn_s_barrier();
                __builtin_amdgcn_sched_barrier(0);
                if (s + 1 < nC) {
                    *(unsigned long long*)&Ab[(s + 1) & 1][adst] = laReg;
                    SW(s + 1, (s + 1) & 1);
                }
                if (s + 3 < nC) laReg = LA(s + 3);
                const int cur = s & 1;
                const int bo = ((wid << 4) + fr) * 64;
                bf16x8 a00 = *(const bf16x8*)&Ab[cur][fr * 64 + sw0];
                bf16x8 a01 = *(const bf16x8*)&Ab[cur][fr * 64 + sw1];
                bf16x8 a10 = *(const bf16x8*)&Ab[cur][(16 + fr) * 64 + sw0];
                bf16x8 a11 = *(const bf16x8*)&Ab[cur][(16 + fr) * 64 + sw1];
                bf16x8 r0 = *(const bf16x8*)&Wb[cur][0][bo + sw0];
                bf16x8 r1 = *(const bf16x8*)&Wb[cur][0][bo + sw1];
                bf16x8 z0 = *(const bf16x8*)&Wb[cur][1][bo + sw0];
                bf16x8 z1 = *(const bf16x8*)&Wb[cur][1][bo + sw1];
                bf16x8 q0 = *(const bf16x8*)&Wb[cur][2][bo + sw0];
                bf16x8 q1 = *(const bf16x8*)&Wb[cur][2][bo + sw1];
                __builtin_amdgcn_s_setprio(1);
                accR[0] = MFMA16(a00, r0, accR[0]); accR[0] = MFMA16(a01, r1, accR[0]);
                accR[1] = MFMA16(a10, r0, accR[1]); accR[1] = MFMA16(a11, r1, accR[1]);
                accZ[0] = MFMA16(a00, z0, accZ[0]); accZ[0] = MFMA16(a01, z1, accZ[0]);
                accZ[1] = MFMA16(a10, z0, accZ[1]); accZ[1] = MFMA16(a11, z1, accZ[1]);
                if (s < nXc) {
                    accI[0] = MFMA16(a00, q0, accI[0]); accI[0] = MFMA16(a01, q1, accI[0]);
                    accI[1] = MFMA16(a10, q0, accI[1]); accI[1] = MFMA16(a11, q1, accI[1]);
                } else {
                    accN[0] = MFMA16(a00, q0, accN[0]); accN[0] = MFMA16(a01, q1, accN[0]);
                    accN[1] = MFMA16(a10, q0, accN[1]); accN[1] = MFMA16(a11, q1, accN[1]);
                }
                __builtin_amdgcn_s_setprio(0);
            };
            for (int s = 0; s < nC; s += 2) { BODY(s, la1); BODY(s + 1, la0); }

            // ring backpressure before overwriting slot t & 31
            if (role <= 1 && t >= RING_) waitflag(&consumed[role * 64 + (t - RING_)], 128);

            // gates + state update; bf16 repack in LDS, fp32 carry stays in LDS
            u16* hrep = &Wb[0][0][0];
#pragma unroll
            for (int m = 0; m < 2; ++m)
#pragma unroll
                for (int i = 0; i < 4; ++i) {
                    int row = m * 16 + kc * 4 + i;
                    float rv = 1.f / (1.f + __expf(-(accR[m][i] + b_r)));
                    float zv = 1.f / (1.f + __expf(-(accZ[m][i] + b_z)));
                    float nv = tanhf(accI[m][i] + b_i + rv * (accN[m][i] + b_h));
                    float hp = carry[row * 132 + (wid << 4) + fr];
                    float hn = (1.f - zv) * nv + zv * hp;
                    carry[row * 132 + (wid << 4) + fr] = hn;
                    hrep[row * 128 + (wid << 4) + fr] = f2b(hn);
                }
            __syncthreads();
            {
                int rr = tid >> 4, jo = (tid & 15) << 3;
                unsigned long long v0 = *(const unsigned long long*)&hrep[rr * 128 + jo];
                unsigned long long v1 = *(const unsigned long long*)&hrep[rr * 128 + jo + 4];
                u16* dst = hout + (size_t)(b0 + rr) * H_ + j0 + jo;
                sysst64(dst, v0);
                sysst64(dst + 4, v1);
            }
            if (t == S_ - 1) {
                int rr = tid >> 4, jo = (tid & 15) << 3;
                float* od = p.out + (size_t)B_ * S_ * O_ + (size_t)role * BH_ +
                            (size_t)(b0 + rr) * H_ + j0 + jo;
                *(float4*)od       = *(const float4*)&carry[rr * 132 + jo];
                *(float4*)(od + 4) = *(const float4*)&carry[rr * 132 + jo + 4];
            }
            asm volatile("s_waitcnt vmcnt(0)" ::: "memory");
            __syncthreads();
            if (tid == 0) {
                postflag(&ready[role * 64 + t]);
                if (role == 0) { if (t) postflag(&consumed[0 * 64 + t - 1]); }
                else if (role == 1) {
                    postflag(&consumed[0 * 64 + t]);
                    if (t) postflag(&consumed[1 * 64 + t - 1]);
                } else {
                    postflag(&consumed[1 * 64 + t]);
                }
            }
            __syncthreads();
        }
    } else {
        // ================= linear head =================
        const int o0 = xcd << 6;         // o-slice fixed per XCD (WLt streaming)
        const int nC = 16;
        const int mg = wid >> 2, og = wid & 3;
        const u16 *A0 = nullptr, *Wl = nullptr;

        auto LAl = [&](int c) -> unsigned long long {
            return sysld64(A0 + (size_t)arow * H_ + (c << 6) + acol);
        };
        auto SWl = [&](int c, int nb) {
            int orow = tid >> 3, c8 = tid & 7;
            gl_lds16(Wl + (size_t)(o0 + orow) * H_ + (c << 6) + ((c8 ^ (orow & 7)) << 3),
                     &Wb[nb][0][tid << 3]);
        };

        for (int t = 0; t < S_; ++t) {
            waitflag(&ready[2 * 64 + t], 64);
            A0 = p.h2a + (size_t)(t + 1) * BH_ + (size_t)b0 * H_;
            Wl = p.WLt + (size_t)t * (O_ * H_);

            f32x4 acc = {0.f, 0.f, 0.f, 0.f};
            unsigned long long la0 = LAl(0), la1 = LAl(1);
            *(unsigned long long*)&Ab[0][adst] = la0;
            SWl(0, 0);
            la0 = LAl(2);

            auto BODYL = [&](int s, unsigned long long& laReg) {
                if (s + 2 < nC) asm volatile("s_waitcnt vmcnt(1)" ::: "memory");
                else            asm volatile("s_waitcnt vmcnt(0)" ::: "memory");
                asm volatile("s_waitcnt lgkmcnt(0)" ::: "memory");
                __builtin_amdgcn_s_barrier();
                __builtin_amdgcn_sched_barrier(0);
                if (s + 1 < nC) {
                    *(unsigned long long*)&Ab[(s + 1) & 1][adst] = laReg;
                    SWl(s + 1, (s + 1) & 1);
                }
                if (s + 3 < nC) laReg = LAl(s + 3);
                const int cur = s & 1;
                bf16x8 a0 = *(const bf16x8*)&Ab[cur][(mg * 16 + fr) * 64 + sw0];
                bf16x8 a1 = *(const bf16x8*)&Ab[cur][(mg * 16 + fr) * 64 + sw1];
                bf16x8 w0 = *(const bf16x8*)&Wb[cur][0][(og * 16 + fr) * 64 + sw0];
                bf16x8 w1 = *(const bf16x8*)&Wb[cur][0][(og * 16 + fr) * 64 + sw1];
                __builtin_amdgcn_s_setprio(1);
                acc = MFMA16(a0, w0, acc);
                acc = MFMA16(a1, w1, acc);
                __builtin_amdgcn_s_setprio(0);
            };
            for (int s = 0; s < nC; s += 2) { BODYL(s, la1); BODYL(s + 1, la0); }

            float bb = p.lb[t * O_ + o0 + og * 16 + fr];
#pragma unroll
            for (int i = 0; i < 4; ++i) {
                int row = mg * 16 + kc * 4 + i;
                p.out[((size_t)(b0 + row) * S_ + t) * O_ + o0 + og * 16 + fr] = acc[i] + bb;
            }
        }
    }
}

// ---------------- launch ----------------

extern "C" void kernel_launch(void* const* d_in, const int* in_sizes, int n_in,
                              void* d_out, int out_size, void* d_ws, size_t ws_size,
                              hipStream_t stream) {
    (void)in_sizes; (void)n_in; (void)out_size; (void)ws_size;
    const float* x   = (const float*)d_in[0];
    const float* wi0 = (const float*)d_in[1];
    const float* wh0 = (const float*)d_in[2];
    const float* bi0 = (const float*)d_in[3];
    const float* bh0 = (const float*)d_in[4];
    const float* wi1 = (const float*)d_in[5];
    const float* wh1 = (const float*)d_in[6];
    const float* bi1 = (const float*)d_in[7];
    const float* bh1 = (const float*)d_in[8];
    const float* wi2 = (const float*)d_in[9];
    const float* wh2 = (const float*)d_in[10];
    const float* bi2 = (const float*)d_in[11];
    const float* bh2 = (const float*)d_in[12];
    const float* lw  = (const float*)d_in[13];
    const float* lb  = (const float*)d_in[14];

    char* base = (char*)d_ws;
    size_t off = 0;
    auto alloc = [&](size_t bytes) {
        char* p = base + off;
        off = (off + bytes + 255) & ~(size_t)255;
        return p;
    };
    u16* Xb  = (u16*)alloc((size_t)B_ * S_ * D_ * 2);
    u16* Wi0 = (u16*)alloc((size_t)G_ * D_ * 2);
    u16* Wh0 = (u16*)alloc((size_t)G_ * H_ * 2);
    u16* Wi1 = (u16*)alloc((size_t)G_ * H_ * 2);
    u16* Wh1 = (u16*)alloc((size_t)G_ * H_ * 2);
    u16* Wi2 = (u16*)alloc((size_t)G_ * H_ * 2);
    u16* Wh2 = (u16*)alloc((size_t)G_ * H_ * 2);
    u16* h0  = (u16*)alloc((size_t)RING_ * BH_ * 2);
    u16* h1  = (u16*)alloc((size_t)RING_ * BH_ * 2);
    u16* h2a = (u16*)alloc((size_t)(S_ + 1) * BH_ * 2);
    u16* WLt = (u16*)alloc((size_t)S_ * O_ * H_ * 2);
    int* flags = (int*)alloc((size_t)(3 * 64 + 2 * 64) * 4);
    int* ready = flags;
    int* consumed = flags + 3 * 64;

    k_conv<<<1024, 256, 0, stream>>>(x,   Xb,  (B_ * S_ * D_) / 4);
    k_conv<<<1024, 256, 0, stream>>>(wi0, Wi0, (G_ * D_) / 4);
    k_conv<<<1024, 256, 0, stream>>>(wh0, Wh0, (G_ * H_) / 4);
    k_conv<<<1024, 256, 0, stream>>>(wi1, Wi1, (G_ * H_) / 4);
    k_conv<<<1024, 256, 0, stream>>>(wh1, Wh1, (G_ * H_) / 4);
    k_conv<<<1024, 256, 0, stream>>>(wi2, Wi2, (G_ * H_) / 4);
    k_conv<<<1024, 256, 0, stream>>>(wh2, Wh2, (G_ * H_) / 4);
    k_twl<<<S_ * 512, 256, 0, stream>>>(lw, WLt);
    hipMemsetAsync(h0 + (size_t)(RING_ - 1) * BH_, 0, (size_t)BH_ * 2, stream);  // h0[-1]=0
    hipMemsetAsync(h1 + (size_t)(RING_ - 1) * BH_, 0, (size_t)BH_ * 2, stream);  // h1[-1]=0
    hipMemsetAsync(h2a, 0, (size_t)BH_ * 2, stream);                             // h2[-1]=0
    hipMemsetAsync(flags, 0, (size_t)(3 * 64 + 2 * 64) * 4, stream);

    GruArgs ga;
    ga.Xb = Xb;
    ga.Wi0 = Wi0; ga.Wh0 = Wh0; ga.Wi1 = Wi1; ga.Wh1 = Wh1; ga.Wi2 = Wi2; ga.Wh2 = Wh2;
    ga.bi0 = bi0; ga.bh0 = bh0; ga.bi1 = bi1; ga.bh1 = bh1; ga.bi2 = bi2; ga.bh2 = bh2;
    ga.h0 = h0; ga.h1 = h1; ga.h2a = h2a;
    ga.WLt = WLt; ga.lb = lb; ga.out = (float*)d_out;
    ga.ready = ready; ga.consumed = consumed;

    void* args[] = {&ga};
    hipLaunchCooperativeKernel((void*)k_gru, dim3(256), dim3(512), args, 0, stream);
}

// Round 7
// 2394.744 us; speedup vs baseline: 1.4027x; 1.0920x over previous
//
#include <hip/hip_runtime.h>
#include <hip/hip_bf16.h>
#include <stdint.h>

#define B_ 256
#define S_ 64
#define D_ 256
#define H_ 1024
#define O_ 512
#define G_ 3072          // 3*H
#define BH_ (B_ * H_)    // 262144
#define RING_ 32

typedef unsigned short u16;
typedef __attribute__((ext_vector_type(8))) short bf16x8;
typedef __attribute__((ext_vector_type(4))) float f32x4;

#define MFMA16(a, b, c) __builtin_amdgcn_mfma_f32_16x16x32_bf16((a), (b), (c), 0, 0, 0)

__device__ __forceinline__ u16 f2b(float f) {
    union { float f; uint32_t u; } v; v.f = f;
    uint32_t u = v.u;
    return (u16)((u + 0x7fffu + ((u >> 16) & 1u)) >> 16);   // RNE
}

__device__ __forceinline__ void gl_lds16(const u16* g, u16* l) {
    __builtin_amdgcn_global_load_lds(
        (const __attribute__((address_space(1))) unsigned int*)g,
        (__attribute__((address_space(3))) unsigned int*)l, 16, 0, 0);
}
// system-coherent 8B load/store: pure vmcnt (global_*), L1/L2-bypassing
__device__ __forceinline__ unsigned long long gld_sys(const u16* p) {
    unsigned long long v;
    asm volatile("global_load_dwordx2 %0, %1, off sc0 sc1"
                 : "=v"(v) : "v"(p) : "memory");
    return v;
}
__device__ __forceinline__ void gst_sys(u16* p, unsigned long long v) {
    asm volatile("global_store_dwordx2 %0, %1, off sc0 sc1"
                 :: "v"(p), "v"(v) : "memory");
}
__device__ __forceinline__ void waitflag(int* f, int n) {
    while (__hip_atomic_load(f, __ATOMIC_RELAXED, __HIP_MEMORY_SCOPE_SYSTEM) < n)
        __builtin_amdgcn_s_sleep(8);
    asm volatile("" ::: "memory");
}
__device__ __forceinline__ void postflag(int* f) {
    __hip_atomic_fetch_add(f, 1, __ATOMIC_RELAXED, __HIP_MEMORY_SCOPE_SYSTEM);
}

// ---------------- prep kernels ----------------

__global__ void k_conv(const float* __restrict__ s, u16* __restrict__ d, int n4) {
    int i = blockIdx.x * blockDim.x + threadIdx.x;
    int st = gridDim.x * blockDim.x;
    for (; i < n4; i += st) {
        float4 v = ((const float4*)s)[i];
        ushort4 o;
        o.x = f2b(v.x); o.y = f2b(v.y); o.z = f2b(v.z); o.w = f2b(v.w);
        ((ushort4*)d)[i] = o;
    }
}

// lin_w [S][H][O] f32 -> [S][O][H] bf16
__global__ __launch_bounds__(256) void k_twl(const float* __restrict__ w, u16* __restrict__ o) {
    __shared__ float tile[32][33];
    int bid = blockIdx.x;
    int t = bid >> 9;
    int rem = bid & 511;
    int j0 = (rem >> 4) << 5;
    int o0 = (rem & 15) << 5;
    int tx = threadIdx.x & 31, ty = threadIdx.x >> 5;
    const float* base = w + (size_t)t * (H_ * O_);
#pragma unroll
    for (int i = 0; i < 4; ++i) {
        int r = ty + (i << 3);
        tile[r][tx] = base[(size_t)(j0 + r) * O_ + o0 + tx];
    }
    __syncthreads();
    u16* ob = o + (size_t)t * (O_ * H_);
#pragma unroll
    for (int i = 0; i < 4; ++i) {
        int r = ty + (i << 3);
        ob[(size_t)(o0 + r) * H_ + j0 + tx] = f2b(tile[tx][r]);
    }
}

// ---------------- persistent dataflow GRU + linear head ----------------
// XCD owns j-slice of every cell's weights; 8 WGs per (cell,XCD) split batch.
// K-loop: 3-buffer Wb, 2-body weight lead, counted vmcnt(7) steady state.

struct GruArgs {
    const u16* Xb;
    const u16 *Wi0, *Wh0, *Wi1, *Wh1, *Wi2, *Wh2;
    const float *bi0, *bh0, *bi1, *bh1, *bi2, *bh2;
    u16 *h0, *h1, *h2a;      // h0,h1: 32-slot rings; h2a: 65 slots (slot t+1 = time t)
    const u16* WLt;          // [S][O][H] bf16
    const float* lb;         // [S][O]
    float* out;              // [B][S][O] then h0,h1,h2 finals
    int* ready;              // [3 cells][64 t]   -> counts to 64
    int* consumed;           // [2 cells][64 t]   -> counts to 128
};

__global__ __launch_bounds__(512, 1) void k_gru(GruArgs p) {
    __shared__ u16 Wb[3][3][128 * 64];   // 144 KiB: 3-deep weight buffers (3 gates)
    __shared__ u16 Ab[2][32 * 64];       // 8 KiB A double-buffer

    const int w = blockIdx.x;
    const int xcd = w & 7;               // weight j-slice owner (targets XCD via %8)
    const int slot = w >> 3;             // 0..31
    const int role = slot >> 3;          // 0,1,2 = GRU cells; 3 = linear head
    const int sub = slot & 7;            // batch tile
    const int b0 = sub * 32;

    const int tid = threadIdx.x;
    const int wid = tid >> 6, lane = tid & 63;
    const int fr = lane & 15, kc = lane >> 4;

    // staging constants (A-tile: 32 rows x 64 k, 8B per thread)
    const int arow = tid >> 4;
    const int acol = (tid & 15) << 2;                                        // u16 offset
    const int adst = arow * 64 + ((((tid & 15) >> 1) ^ (arow & 7)) << 3) + ((tid & 1) << 2);

    int sw0 = ((kc ^ (fr & 7)) << 3);
    int sw1 = (((4 + kc) ^ (fr & 7)) << 3);

    int* ready = p.ready;
    int* consumed = p.consumed;

    if (role < 3) {
        // ================= GRU cell =================
        const u16 *Wi, *Wh; const float *bi, *bh; int K0;
        if (role == 0)      { Wi = p.Wi0; Wh = p.Wh0; bi = p.bi0; bh = p.bh0; K0 = D_; }
        else if (role == 1) { Wi = p.Wi1; Wh = p.Wh1; bi = p.bi1; bh = p.bh1; K0 = H_; }
        else                { Wi = p.Wi2; Wh = p.Wh2; bi = p.bi2; bh = p.bh2; K0 = H_; }
        const int nXc = K0 >> 6;
        const int nC = nXc + 16;         // 20 or 32 (even)
        const int j0 = xcd * 128;        // weight slice fixed per XCD
        const int jme = j0 + (wid << 4) + fr;
        const float b_r = bi[jme] + bh[jme];
        const float b_z = bi[H_ + jme] + bh[H_ + jme];
        const float b_i = bi[2 * H_ + jme];
        const float b_h = bh[2 * H_ + jme];

        const u16 *A0 = nullptr, *Ah = nullptr; int ld0 = H_;
        u16* hout = nullptr;

        f32x4 hcar[2] = {};              // fp32 recurrent carry in registers

        auto LA = [&](int c) -> unsigned long long {
            const u16* s = (c < nXc) ? (A0 + (size_t)arow * ld0 + (c << 6) + acol)
                                     : (Ah + (size_t)arow * H_ + ((c - nXc) << 6) + acol);
            return gld_sys(s);
        };
        auto SW = [&](int c, int nb) {
            if (c < nXc) {
                int ko = c << 6;
#pragma unroll
                for (int hh = 0; hh < 2; ++hh) {
                    int ci = (hh << 9) + tid, jr = ci >> 3, c8 = ci & 7;
                    size_t ro = (size_t)(j0 + jr) * K0 + ko + ((c8 ^ (jr & 7)) << 3);
                    gl_lds16(Wi + ro,                       &Wb[nb][0][ci << 3]);
                    gl_lds16(Wi + (size_t)H_ * K0 + ro,     &Wb[nb][1][ci << 3]);
                    gl_lds16(Wi + (size_t)2 * H_ * K0 + ro, &Wb[nb][2][ci << 3]);
                }
            } else {
                int ko = (c - nXc) << 6;
#pragma unroll
                for (int hh = 0; hh < 2; ++hh) {
                    int ci = (hh << 9) + tid, jr = ci >> 3, c8 = ci & 7;
                    size_t ro = (size_t)(j0 + jr) * H_ + ko + ((c8 ^ (jr & 7)) << 3);
                    gl_lds16(Wh + ro,                       &Wb[nb][0][ci << 3]);
                    gl_lds16(Wh + (size_t)H_ * H_ + ro,     &Wb[nb][1][ci << 3]);
                    gl_lds16(Wh + (size_t)2 * H_ * H_ + ro, &Wb[nb][2][ci << 3]);
                }
            }
        };

        for (int t = 0; t < S_; ++t) {
            if (role == 0) {
                if (t) waitflag(&ready[0 * 64 + t - 1], 64);
                A0 = p.Xb + (size_t)b0 * (S_ * D_) + t * D_; ld0 = S_ * D_;
                Ah = p.h0 + (size_t)((t + RING_ - 1) & (RING_ - 1)) * BH_ + (size_t)b0 * H_;
                hout = p.h0 + (size_t)(t & (RING_ - 1)) * BH_;
            } else if (role == 1) {
                waitflag(&ready[0 * 64 + t], 64);
                if (t) waitflag(&ready[1 * 64 + t - 1], 64);
                A0 = p.h0 + (size_t)(t & (RING_ - 1)) * BH_ + (size_t)b0 * H_; ld0 = H_;
                Ah = p.h1 + (size_t)((t + RING_ - 1) & (RING_ - 1)) * BH_ + (size_t)b0 * H_;
                hout = p.h1 + (size_t)(t & (RING_ - 1)) * BH_;
            } else {
                waitflag(&ready[1 * 64 + t], 64);
                if (t) waitflag(&ready[2 * 64 + t - 1], 64);
                A0 = p.h1 + (size_t)(t & (RING_ - 1)) * BH_ + (size_t)b0 * H_; ld0 = H_;
                Ah = p.h2a + (size_t)t * BH_ + (size_t)b0 * H_;
                hout = p.h2a + (size_t)(t + 1) * BH_;
            }

            f32x4 accR[2] = {}, accZ[2] = {}, accI[2] = {}, accN[2] = {};

            // prologue: SW(0) [6], LA(0..2) [3], SW(1) [6] -> 15 vm ops
            SW(0, 0);
            unsigned long long la_t = LA(0);
            unsigned long long r1 = LA(1);
            unsigned long long r0 = LA(2);
            SW(1, 1);
            asm volatile("s_waitcnt vmcnt(8)" ::: "memory");   // LA(0)+SW(0) done
            *(unsigned long long*)&Ab[0][adst] = la_t;
            asm volatile("s_waitcnt lgkmcnt(0)" ::: "memory");
            __builtin_amdgcn_sched_barrier(0);

            auto BODY = [&](int s, unsigned long long& laReg) {
                if (s + 2 < nC) asm volatile("s_waitcnt vmcnt(7)" ::: "memory");
                else            asm volatile("s_waitcnt vmcnt(0)" ::: "memory");
                __builtin_amdgcn_s_barrier();
                __builtin_amdgcn_sched_barrier(0);
                if (s + 1 < nC) *(unsigned long long*)&Ab[(s + 1) & 1][adst] = laReg;
                if (s + 3 < nC) laReg = LA(s + 3);
                if (s + 2 < nC) SW(s + 2, (s + 2) % 3);
                __builtin_amdgcn_sched_barrier(0);
                const int cur = s & 1;
                const int wcur = s % 3;
                const int bo = ((wid << 4) + fr) * 64;
                bf16x8 a00 = *(const bf16x8*)&Ab[cur][fr * 64 + sw0];
                bf16x8 a01 = *(const bf16x8*)&Ab[cur][fr * 64 + sw1];
                bf16x8 a10 = *(const bf16x8*)&Ab[cur][(16 + fr) * 64 + sw0];
                bf16x8 a11 = *(const bf16x8*)&Ab[cur][(16 + fr) * 64 + sw1];
                bf16x8 rr0 = *(const bf16x8*)&Wb[wcur][0][bo + sw0];
                bf16x8 rr1 = *(const bf16x8*)&Wb[wcur][0][bo + sw1];
                bf16x8 zz0 = *(const bf16x8*)&Wb[wcur][1][bo + sw0];
                bf16x8 zz1 = *(const bf16x8*)&Wb[wcur][1][bo + sw1];
                bf16x8 qq0 = *(const bf16x8*)&Wb[wcur][2][bo + sw0];
                bf16x8 qq1 = *(const bf16x8*)&Wb[wcur][2][bo + sw1];
                asm volatile("s_waitcnt lgkmcnt(0)" ::: "memory");
                __builtin_amdgcn_sched_barrier(0);
                __builtin_amdgcn_s_setprio(1);
                accR[0] = MFMA16(a00, rr0, accR[0]); accR[0] = MFMA16(a01, rr1, accR[0]);
                accR[1] = MFMA16(a10, rr0, accR[1]); accR[1] = MFMA16(a11, rr1, accR[1]);
                accZ[0] = MFMA16(a00, zz0, accZ[0]); accZ[0] = MFMA16(a01, zz1, accZ[0]);
                accZ[1] = MFMA16(a10, zz0, accZ[1]); accZ[1] = MFMA16(a11, zz1, accZ[1]);
                if (s < nXc) {
                    accI[0] = MFMA16(a00, qq0, accI[0]); accI[0] = MFMA16(a01, qq1, accI[0]);
                    accI[1] = MFMA16(a10, qq0, accI[1]); accI[1] = MFMA16(a11, qq1, accI[1]);
                } else {
                    accN[0] = MFMA16(a00, qq0, accN[0]); accN[0] = MFMA16(a01, qq1, accN[0]);
                    accN[1] = MFMA16(a10, qq0, accN[1]); accN[1] = MFMA16(a11, qq1, accN[1]);
                }
                __builtin_amdgcn_s_setprio(0);
            };
            for (int s = 0; s < nC; s += 2) { BODY(s, r1); BODY(s + 1, r0); }

            // ring backpressure before overwriting slot t & 31
            if (role <= 1 && t >= RING_) waitflag(&consumed[role * 64 + (t - RING_)], 128);

            // gates + state update; fp32 carry in regs, bf16 repack via LDS (Wb[0])
            u16* hrep = &Wb[0][0][0];
#pragma unroll
            for (int m = 0; m < 2; ++m)
#pragma unroll
                for (int i = 0; i < 4; ++i) {
                    int row = m * 16 + kc * 4 + i;
                    float rv = 1.f / (1.f + __expf(-(accR[m][i] + b_r)));
                    float zv = 1.f / (1.f + __expf(-(accZ[m][i] + b_z)));
                    float nv = tanhf(accI[m][i] + b_i + rv * (accN[m][i] + b_h));
                    float hn = (1.f - zv) * nv + zv * hcar[m][i];
                    hcar[m][i] = hn;
                    hrep[row * 128 + (wid << 4) + fr] = f2b(hn);
                }
            __syncthreads();
            {
                int rr = tid >> 4, jo = (tid & 15) << 3;
                unsigned long long v0 = *(const unsigned long long*)&hrep[rr * 128 + jo];
                unsigned long long v1 = *(const unsigned long long*)&hrep[rr * 128 + jo + 4];
                u16* dst = hout + (size_t)(b0 + rr) * H_ + j0 + jo;
                gst_sys(dst, v0);
                gst_sys(dst + 4, v1);
            }
            if (t == S_ - 1) {
                float* ob = p.out + (size_t)B_ * S_ * O_ + (size_t)role * BH_;
#pragma unroll
                for (int m = 0; m < 2; ++m)
#pragma unroll
                    for (int i = 0; i < 4; ++i) {
                        int row = m * 16 + kc * 4 + i;
                        ob[(size_t)(b0 + row) * H_ + jme] = hcar[m][i];
                    }
            }
            asm volatile("s_waitcnt vmcnt(0)" ::: "memory");
            __syncthreads();
            if (tid == 0) {
                postflag(&ready[role * 64 + t]);
                if (role == 0) { if (t) postflag(&consumed[0 * 64 + t - 1]); }
                else if (role == 1) {
                    postflag(&consumed[0 * 64 + t]);
                    if (t) postflag(&consumed[1 * 64 + t - 1]);
                } else {
                    postflag(&consumed[1 * 64 + t]);
                }
            }
            __syncthreads();
        }
    } else {
        // ================= linear head =================
        const int o0 = xcd << 6;         // o-slice fixed per XCD
        const int nC = 16;
        const int mg = wid >> 2, og = wid & 3;
        const u16 *A0 = nullptr, *Wl = nullptr;

        auto LAl = [&](int c) -> unsigned long long {
            return gld_sys(A0 + (size_t)arow * H_ + (c << 6) + acol);
        };
        auto SWl = [&](int c, int nb) {
            int orow = tid >> 3, c8 = tid & 7;
            gl_lds16(Wl + (size_t)(o0 + orow) * H_ + (c << 6) + ((c8 ^ (orow & 7)) << 3),
                     &Wb[nb][0][tid << 3]);
        };

        for (int t = 0; t < S_; ++t) {
            waitflag(&ready[2 * 64 + t], 64);
            A0 = p.h2a + (size_t)(t + 1) * BH_ + (size_t)b0 * H_;
            Wl = p.WLt + (size_t)t * (O_ * H_);

            f32x4 acc = {0.f, 0.f, 0.f, 0.f};
            // prologue: SWl(0) [1], LA(0..2) [3], SWl(1) [1] -> 5 vm ops
            SWl(0, 0);
            unsigned long long la_t = LAl(0);
            unsigned long long r1 = LAl(1);
            unsigned long long r0 = LAl(2);
            SWl(1, 1);
            asm volatile("s_waitcnt vmcnt(3)" ::: "memory");   // LAl(0)+SWl(0) done
            *(unsigned long long*)&Ab[0][adst] = la_t;
            asm volatile("s_waitcnt lgkmcnt(0)" ::: "memory");
            __builtin_amdgcn_sched_barrier(0);

            auto BODYL = [&](int s, unsigned long long& laReg) {
                if (s + 2 < nC) asm volatile("s_waitcnt vmcnt(2)" ::: "memory");
                else            asm volatile("s_waitcnt vmcnt(0)" ::: "memory");
                __builtin_amdgcn_s_barrier();
                __builtin_amdgcn_sched_barrier(0);
                if (s + 1 < nC) *(unsigned long long*)&Ab[(s + 1) & 1][adst] = laReg;
                if (s + 3 < nC) laReg = LAl(s + 3);
                if (s + 2 < nC) SWl(s + 2, (s + 2) % 3);
                __builtin_amdgcn_sched_barrier(0);
                const int cur = s & 1;
                const int wcur = s % 3;
                bf16x8 a0 = *(const bf16x8*)&Ab[cur][(mg * 16 + fr) * 64 + sw0];
                bf16x8 a1 = *(const bf16x8*)&Ab[cur][(mg * 16 + fr) * 64 + sw1];
                bf16x8 w0 = *(const bf16x8*)&Wb[wcur][0][(og * 16 + fr) * 64 + sw0];
                bf16x8 w1 = *(const bf16x8*)&Wb[wcur][0][(og * 16 + fr) * 64 + sw1];
                asm volatile("s_waitcnt lgkmcnt(0)" ::: "memory");
                __builtin_amdgcn_sched_barrier(0);
                __builtin_amdgcn_s_setprio(1);
                acc = MFMA16(a0, w0, acc);
                acc = MFMA16(a1, w1, acc);
                __builtin_amdgcn_s_setprio(0);
            };
            for (int s = 0; s < nC; s += 2) { BODYL(s, r1); BODYL(s + 1, r0); }

            float bb = p.lb[t * O_ + o0 + og * 16 + fr];
#pragma unroll
            for (int i = 0; i < 4; ++i) {
                int row = mg * 16 + kc * 4 + i;
                p.out[((size_t)(b0 + row) * S_ + t) * O_ + o0 + og * 16 + fr] = acc[i] + bb;
            }
        }
    }
}

// ---------------- launch ----------------

extern "C" void kernel_launch(void* const* d_in, const int* in_sizes, int n_in,
                              void* d_out, int out_size, void* d_ws, size_t ws_size,
                              hipStream_t stream) {
    (void)in_sizes; (void)n_in; (void)out_size; (void)ws_size;
    const float* x   = (const float*)d_in[0];
    const float* wi0 = (const float*)d_in[1];
    const float* wh0 = (const float*)d_in[2];
    const float* bi0 = (const float*)d_in[3];
    const float* bh0 = (const float*)d_in[4];
    const float* wi1 = (const float*)d_in[5];
    const float* wh1 = (const float*)d_in[6];
    const float* bi1 = (const float*)d_in[7];
    const float* bh1 = (const float*)d_in[8];
    const float* wi2 = (const float*)d_in[9];
    const float* wh2 = (const float*)d_in[10];
    const float* bi2 = (const float*)d_in[11];
    const float* bh2 = (const float*)d_in[12];
    const float* lw  = (const float*)d_in[13];
    const float* lb  = (const float*)d_in[14];

    char* base = (char*)d_ws;
    size_t off = 0;
    auto alloc = [&](size_t bytes) {
        char* p = base + off;
        off = (off + bytes + 255) & ~(size_t)255;
        return p;
    };
    u16* Xb  = (u16*)alloc((size_t)B_ * S_ * D_ * 2);
    u16* Wi0 = (u16*)alloc((size_t)G_ * D_ * 2);
    u16* Wh0 = (u16*)alloc((size_t)G_ * H_ * 2);
    u16* Wi1 = (u16*)alloc((size_t)G_ * H_ * 2);
    u16* Wh1 = (u16*)alloc((size_t)G_ * H_ * 2);
    u16* Wi2 = (u16*)alloc((size_t)G_ * H_ * 2);
    u16* Wh2 = (u16*)alloc((size_t)G_ * H_ * 2);
    u16* h0  = (u16*)alloc((size_t)RING_ * BH_ * 2);
    u16* h1  = (u16*)alloc((size_t)RING_ * BH_ * 2);
    u16* h2a = (u16*)alloc((size_t)(S_ + 1) * BH_ * 2);
    u16* WLt = (u16*)alloc((size_t)S_ * O_ * H_ * 2);
    int* flags = (int*)alloc((size_t)(3 * 64 + 2 * 64) * 4);
    int* ready = flags;
    int* consumed = flags + 3 * 64;

    k_conv<<<1024, 256, 0, stream>>>(x,   Xb,  (B_ * S_ * D_) / 4);
    k_conv<<<1024, 256, 0, stream>>>(wi0, Wi0, (G_ * D_) / 4);
    k_conv<<<1024, 256, 0, stream>>>(wh0, Wh0, (G_ * H_) / 4);
    k_conv<<<1024, 256, 0, stream>>>(wi1, Wi1, (G_ * H_) / 4);
    k_conv<<<1024, 256, 0, stream>>>(wh1, Wh1, (G_ * H_) / 4);
    k_conv<<<1024, 256, 0, stream>>>(wi2, Wi2, (G_ * H_) / 4);
    k_conv<<<1024, 256, 0, stream>>>(wh2, Wh2, (G_ * H_) / 4);
    k_twl<<<S_ * 512, 256, 0, stream>>>(lw, WLt);
    hipMemsetAsync(h0 + (size_t)(RING_ - 1) * BH_, 0, (size_t)BH_ * 2, stream);  // h0[-1]=0
    hipMemsetAsync(h1 + (size_t)(RING_ - 1) * BH_, 0, (size_t)BH_ * 2, stream);  // h1[-1]=0
    hipMemsetAsync(h2a, 0, (size_t)BH_ * 2, stream);                             // h2[-1]=0
    hipMemsetAsync(flags, 0, (size_t)(3 * 64 + 2 * 64) * 4, stream);

    GruArgs ga;
    ga.Xb = Xb;
    ga.Wi0 = Wi0; ga.Wh0 = Wh0; ga.Wi1 = Wi1; ga.Wh1 = Wh1; ga.Wi2 = Wi2; ga.Wh2 = Wh2;
    ga.bi0 = bi0; ga.bh0 = bh0; ga.bi1 = bi1; ga.bh1 = bh1; ga.bi2 = bi2; ga.bh2 = bh2;
    ga.h0 = h0; ga.h1 = h1; ga.h2a = h2a;
    ga.WLt = WLt; ga.lb = lb; ga.out = (float*)d_out;
    ga.ready = ready; ga.consumed = consumed;

    void* args[] = {&ga};
    hipLaunchCooperativeKernel((void*)k_gru, dim3(256), dim3(512), args, 0, stream);
}